// Round 1
// baseline (1695.380 us; speedup 1.0000x reference)
//
#include <hip/hip_runtime.h>
#include <math.h>

#define S_LEN   2048
#define B_SZ    2
#define D_MODEL 768
#define N_HEADS 12
#define DK      64
#define DFF     3072
#define N_TOK   (S_LEN * B_SZ)   // 4096
#define EPS     1e-5f
#define SCALE   0.125f           // 1/sqrt(64)

// ---------------------------------------------------------------------------
// LayerNorm: one block (256 threads) per row of 768
// ---------------------------------------------------------------------------
__global__ __launch_bounds__(256) void ln_kernel(
    const float* __restrict__ x, const float* __restrict__ g,
    const float* __restrict__ b, float* __restrict__ z)
{
    int row = blockIdx.x;
    const float* xr = x + (size_t)row * D_MODEL;
    float*       zr = z + (size_t)row * D_MODEL;
    int t = threadIdx.x;

    float loc[3];
    float s1 = 0.f, s2 = 0.f;
#pragma unroll
    for (int i = 0; i < 3; ++i) {
        float v = xr[t + 256 * i];
        loc[i] = v; s1 += v; s2 += v * v;
    }
#pragma unroll
    for (int off = 32; off > 0; off >>= 1) {
        s1 += __shfl_down(s1, off);
        s2 += __shfl_down(s2, off);
    }
    __shared__ float r1[4], r2[4];
    __shared__ float mu_s, is_s;
    int wave = t >> 6, lane = t & 63;
    if (lane == 0) { r1[wave] = s1; r2[wave] = s2; }
    __syncthreads();
    if (t == 0) {
        float a = r1[0] + r1[1] + r1[2] + r1[3];
        float c = r2[0] + r2[1] + r2[2] + r2[3];
        float mu  = a * (1.f / D_MODEL);
        float var = c * (1.f / D_MODEL) - mu * mu;
        mu_s = mu;
        is_s = rsqrtf(var + EPS);
    }
    __syncthreads();
    float mu = mu_s, istd = is_s;
#pragma unroll
    for (int i = 0; i < 3; ++i) {
        int c = t + 256 * i;
        zr[c] = (loc[i] - mu) * istd * g[c] + b[c];
    }
}

// ---------------------------------------------------------------------------
// Generic NT GEMM: C[M,Ncols] = A[M,K] * W[Ncols,K]^T + bias (+ELU) (+res)
// 64x64 tile, BK=16, 256 threads, 4x4 micro-tile, fp32 vector ALU
// ---------------------------------------------------------------------------
template <bool ELU_ACT, bool RES>
__global__ __launch_bounds__(256) void gemm_nt(
    const float* __restrict__ A, const float* __restrict__ W,
    const float* __restrict__ bias, const float* __restrict__ res,
    float* __restrict__ C, int M, int Ncols, int K)
{
    (void)M;
    __shared__ float As[16][68];   // k-major, pad to keep float4 rows aligned
    __shared__ float Ws[16][68];

    int bn = blockIdx.x, bm = blockIdx.y;
    int row0 = bm * 64, col0 = bn * 64;
    int t  = threadIdx.x;
    int tx = t & 15, ty = t >> 4;      // micro-tile: rows 4*ty+i, cols 4*tx+j
    int lr = t >> 2, lc4 = t & 3;      // loader: row lr, float4 #lc4 within 16 k

    const float* Arow = A + (size_t)(row0 + lr) * K + lc4 * 4;
    const float* Wrow = W + (size_t)(col0 + lr) * K + lc4 * 4;

    float acc[4][4] = {};
    float4 av = *(const float4*)(Arow);
    float4 wv = *(const float4*)(Wrow);

    for (int k0 = 0; k0 < K; k0 += 16) {
        __syncthreads();   // previous iteration's compute done
        As[lc4 * 4 + 0][lr] = av.x; As[lc4 * 4 + 1][lr] = av.y;
        As[lc4 * 4 + 2][lr] = av.z; As[lc4 * 4 + 3][lr] = av.w;
        Ws[lc4 * 4 + 0][lr] = wv.x; Ws[lc4 * 4 + 1][lr] = wv.y;
        Ws[lc4 * 4 + 2][lr] = wv.z; Ws[lc4 * 4 + 3][lr] = wv.w;
        if (k0 + 16 < K) {             // prefetch next tile
            av = *(const float4*)(Arow + k0 + 16);
            wv = *(const float4*)(Wrow + k0 + 16);
        }
        __syncthreads();
#pragma unroll
        for (int kk = 0; kk < 16; ++kk) {
            float4 a = *(const float4*)&As[kk][4 * ty];
            float4 w = *(const float4*)&Ws[kk][4 * tx];
            acc[0][0] += a.x * w.x; acc[0][1] += a.x * w.y;
            acc[0][2] += a.x * w.z; acc[0][3] += a.x * w.w;
            acc[1][0] += a.y * w.x; acc[1][1] += a.y * w.y;
            acc[1][2] += a.y * w.z; acc[1][3] += a.y * w.w;
            acc[2][0] += a.z * w.x; acc[2][1] += a.z * w.y;
            acc[2][2] += a.z * w.z; acc[2][3] += a.z * w.w;
            acc[3][0] += a.w * w.x; acc[3][1] += a.w * w.y;
            acc[3][2] += a.w * w.z; acc[3][3] += a.w * w.w;
        }
    }

    float4 bb = *(const float4*)&bias[col0 + 4 * tx];
#pragma unroll
    for (int i = 0; i < 4; ++i) {
        int r = row0 + 4 * ty + i;
        float4 o;
        o.x = acc[i][0] + bb.x; o.y = acc[i][1] + bb.y;
        o.z = acc[i][2] + bb.z; o.w = acc[i][3] + bb.w;
        if (ELU_ACT) {
            o.x = o.x > 0.f ? o.x : expm1f(o.x);
            o.y = o.y > 0.f ? o.y : expm1f(o.y);
            o.z = o.z > 0.f ? o.z : expm1f(o.z);
            o.w = o.w > 0.f ? o.w : expm1f(o.w);
        }
        if (RES) {
            float4 rv = *(const float4*)&res[(size_t)r * Ncols + col0 + 4 * tx];
            o.x += rv.x; o.y += rv.y; o.z += rv.z; o.w += rv.w;
        }
        *(float4*)&C[(size_t)r * Ncols + col0 + 4 * tx] = o;
    }
}

// ---------------------------------------------------------------------------
// Flash-style attention, fp32. Block = (qblock of 64 rows, b, h), 256 threads.
// Online softmax, m/l in registers (replicated across 16-lane row groups).
// ---------------------------------------------------------------------------
__global__ __launch_bounds__(256) void attn_kernel(
    const float* __restrict__ q, const float* __restrict__ k,
    const float* __restrict__ v, float* __restrict__ ctx)
{
    __shared__ float Qs[64][65];
    __shared__ float KPs[64][65];   // K tile, then reused for P
    __shared__ float Vs[64][65];

    int qb = blockIdx.x;
    int bh = blockIdx.y;
    int b = bh & 1, h = bh >> 1;
    int t = threadIdx.x;
    int tx = t & 15, ty = t >> 4;   // score tile: rows ty+16i, cols tx+16j

    int base_q = ((qb * 64) * B_SZ + b) * D_MODEL + h * DK;
#pragma unroll
    for (int i = 0; i < 4; ++i) {
        int idx = t + i * 256;
        int r = idx >> 4, c4 = idx & 15;
        float4 vv = *(const float4*)&q[base_q + r * B_SZ * D_MODEL + c4 * 4];
        Qs[r][c4 * 4 + 0] = vv.x; Qs[r][c4 * 4 + 1] = vv.y;
        Qs[r][c4 * 4 + 2] = vv.z; Qs[r][c4 * 4 + 3] = vv.w;
    }

    float m_i[4], l_i[4], O[4][4];
#pragma unroll
    for (int i = 0; i < 4; ++i) {
        m_i[i] = -INFINITY; l_i[i] = 0.f;
#pragma unroll
        for (int j = 0; j < 4; ++j) O[i][j] = 0.f;
    }

    for (int kb = 0; kb < S_LEN / 64; ++kb) {
        __syncthreads();   // Qs visible (iter 0); KPs/Vs free (later iters)
        int base_k = ((kb * 64) * B_SZ + b) * D_MODEL + h * DK;
#pragma unroll
        for (int i = 0; i < 4; ++i) {
            int idx = t + i * 256;
            int r = idx >> 4, c4 = idx & 15;
            float4 kv = *(const float4*)&k[base_k + r * B_SZ * D_MODEL + c4 * 4];
            float4 vv = *(const float4*)&v[base_k + r * B_SZ * D_MODEL + c4 * 4];
            KPs[r][c4 * 4 + 0] = kv.x; KPs[r][c4 * 4 + 1] = kv.y;
            KPs[r][c4 * 4 + 2] = kv.z; KPs[r][c4 * 4 + 3] = kv.w;
            Vs[r][c4 * 4 + 0] = vv.x; Vs[r][c4 * 4 + 1] = vv.y;
            Vs[r][c4 * 4 + 2] = vv.z; Vs[r][c4 * 4 + 3] = vv.w;
        }
        __syncthreads();

        // S = Q K^T * scale   (4x4 per thread, in registers)
        float s[4][4] = {};
#pragma unroll 8
        for (int kk = 0; kk < 64; ++kk) {
            float a0 = Qs[ty +  0][kk], a1 = Qs[ty + 16][kk];
            float a2 = Qs[ty + 32][kk], a3 = Qs[ty + 48][kk];
            float w0 = KPs[tx +  0][kk], w1 = KPs[tx + 16][kk];
            float w2 = KPs[tx + 32][kk], w3 = KPs[tx + 48][kk];
            s[0][0] += a0 * w0; s[0][1] += a0 * w1; s[0][2] += a0 * w2; s[0][3] += a0 * w3;
            s[1][0] += a1 * w0; s[1][1] += a1 * w1; s[1][2] += a1 * w2; s[1][3] += a1 * w3;
            s[2][0] += a2 * w0; s[2][1] += a2 * w1; s[2][2] += a2 * w2; s[2][3] += a2 * w3;
            s[3][0] += a3 * w0; s[3][1] += a3 * w1; s[3][2] += a3 * w2; s[3][3] += a3 * w3;
        }

        // online softmax, per row (16 lanes per row -> shfl_xor 1/2/4/8)
#pragma unroll
        for (int i = 0; i < 4; ++i) {
            float mx = fmaxf(fmaxf(s[i][0] , s[i][1]), fmaxf(s[i][2], s[i][3])) * SCALE;
            mx = fmaxf(mx, __shfl_xor(mx, 1));
            mx = fmaxf(mx, __shfl_xor(mx, 2));
            mx = fmaxf(mx, __shfl_xor(mx, 4));
            mx = fmaxf(mx, __shfl_xor(mx, 8));
            float mnew = fmaxf(m_i[i], mx);
            float alpha = (m_i[i] == -INFINITY) ? 0.f : __expf(m_i[i] - mnew);
            float sum = 0.f;
#pragma unroll
            for (int j = 0; j < 4; ++j) {
                float p = __expf(s[i][j] * SCALE - mnew);
                s[i][j] = p;
                sum += p;
            }
            sum += __shfl_xor(sum, 1);
            sum += __shfl_xor(sum, 2);
            sum += __shfl_xor(sum, 4);
            sum += __shfl_xor(sum, 8);
            m_i[i] = mnew;
            l_i[i] = l_i[i] * alpha + sum;
#pragma unroll
            for (int j = 0; j < 4; ++j) O[i][j] *= alpha;
        }

        __syncthreads();   // all threads done reading KPs as K
#pragma unroll
        for (int i = 0; i < 4; ++i)
#pragma unroll
            for (int j = 0; j < 4; ++j)
                KPs[ty + 16 * i][tx + 16 * j] = s[i][j];
        __syncthreads();

        // O += P V
#pragma unroll 8
        for (int kk = 0; kk < 64; ++kk) {
            float p0 = KPs[ty +  0][kk], p1 = KPs[ty + 16][kk];
            float p2 = KPs[ty + 32][kk], p3 = KPs[ty + 48][kk];
            float v0 = Vs[kk][tx +  0], v1 = Vs[kk][tx + 16];
            float v2 = Vs[kk][tx + 32], v3 = Vs[kk][tx + 48];
            O[0][0] += p0 * v0; O[0][1] += p0 * v1; O[0][2] += p0 * v2; O[0][3] += p0 * v3;
            O[1][0] += p1 * v0; O[1][1] += p1 * v1; O[1][2] += p1 * v2; O[1][3] += p1 * v3;
            O[2][0] += p2 * v0; O[2][1] += p2 * v1; O[2][2] += p2 * v2; O[2][3] += p2 * v3;
            O[3][0] += p3 * v0; O[3][1] += p3 * v1; O[3][2] += p3 * v2; O[3][3] += p3 * v3;
        }
    }

    int base_o = ((qb * 64) * B_SZ + b) * D_MODEL + h * DK;
#pragma unroll
    for (int i = 0; i < 4; ++i) {
        float inv = 1.f / l_i[i];
#pragma unroll
        for (int j = 0; j < 4; ++j)
            ctx[base_o + (ty + 16 * i) * B_SZ * D_MODEL + tx + 16 * j] = O[i][j] * inv;
    }
}

// ---------------------------------------------------------------------------
extern "C" void kernel_launch(void* const* d_in, const int* in_sizes, int n_in,
                              void* d_out, int out_size, void* d_ws, size_t ws_size,
                              hipStream_t stream)
{
    (void)in_sizes; (void)n_in; (void)out_size; (void)ws_size;
    const float* x   = (const float*)d_in[0];
    const float* wq  = (const float*)d_in[1];
    const float* bq  = (const float*)d_in[2];
    const float* wk  = (const float*)d_in[3];
    const float* bk  = (const float*)d_in[4];
    const float* wv  = (const float*)d_in[5];
    const float* bv  = (const float*)d_in[6];
    const float* wo  = (const float*)d_in[7];
    const float* bo  = (const float*)d_in[8];
    const float* g1  = (const float*)d_in[9];
    const float* b1  = (const float*)d_in[10];
    const float* g2  = (const float*)d_in[11];
    const float* b2  = (const float*)d_in[12];
    const float* w1  = (const float*)d_in[13];
    const float* bb1 = (const float*)d_in[14];
    const float* w2  = (const float*)d_in[15];
    const float* bb2 = (const float*)d_in[16];
    float* out = (float*)d_out;
    float* ws  = (float*)d_ws;

    const size_t ND = (size_t)N_TOK * D_MODEL;
    float* zb = ws;            // z1 -> later attention ctx
    float* qb = ws + ND;       // q  -> later z2
    float* kb = ws + 2 * ND;
    float* vb = ws + 3 * ND;
    float* hb = ws + 4 * ND;   // FFN hidden chunk (1024 x 3072)

    dim3 blk(256);

    // z1 = LN(x)
    ln_kernel<<<N_TOK, blk, 0, stream>>>(x, g1, b1, zb);
    // q,k,v = z1 @ W^T + b
    dim3 gproj(D_MODEL / 64, N_TOK / 64);
    gemm_nt<false, false><<<gproj, blk, 0, stream>>>(zb, wq, bq, nullptr, qb, N_TOK, D_MODEL, D_MODEL);
    gemm_nt<false, false><<<gproj, blk, 0, stream>>>(zb, wk, bk, nullptr, kb, N_TOK, D_MODEL, D_MODEL);
    gemm_nt<false, false><<<gproj, blk, 0, stream>>>(zb, wv, bv, nullptr, vb, N_TOK, D_MODEL, D_MODEL);
    // ctx = softmax(QK^T/8) V   (ctx overwrites z1)
    attn_kernel<<<dim3(S_LEN / 64, B_SZ * N_HEADS), blk, 0, stream>>>(qb, kb, vb, zb);
    // x1 = x + ctx @ wo^T + bo  (-> d_out)
    gemm_nt<false, true><<<gproj, blk, 0, stream>>>(zb, wo, bo, x, out, N_TOK, D_MODEL, D_MODEL);
    // z2 = LN(x1) -> qb
    ln_kernel<<<N_TOK, blk, 0, stream>>>(out, g2, b2, qb);
    // FFN in row-chunks of 1024 to bound workspace
    const int MCH = 1024;
    for (int c0 = 0; c0 < N_TOK; c0 += MCH) {
        gemm_nt<true, false><<<dim3(DFF / 64, MCH / 64), blk, 0, stream>>>(
            qb + (size_t)c0 * D_MODEL, w1, bb1, nullptr, hb, MCH, DFF, D_MODEL);
        gemm_nt<false, true><<<dim3(D_MODEL / 64, MCH / 64), blk, 0, stream>>>(
            hb, w2, bb2, out + (size_t)c0 * D_MODEL, out + (size_t)c0 * D_MODEL, MCH, D_MODEL, DFF);
    }
}

// Round 2
// 269.047 us; speedup vs baseline: 6.3014x; 6.3014x over previous
//
#include <hip/hip_runtime.h>
#include <hip/hip_bf16.h>
#include <math.h>

#define S_LEN   2048
#define B_SZ    2
#define D_MODEL 768
#define N_HEADS 12
#define DFF     3072
#define N_TOK   4096
#define EPS     1e-5f
#define SCALE   0.125f
#define QKV_N   2304

typedef __attribute__((ext_vector_type(8))) short short8;
typedef __attribute__((ext_vector_type(4))) float f32x4;

__device__ __forceinline__ void gload16(const void* g, void* l) {
    __builtin_amdgcn_global_load_lds(
        (const __attribute__((address_space(1))) void*)g,
        (__attribute__((address_space(3))) void*)l, 16, 0, 0);
}
__device__ __forceinline__ unsigned short f2bf(float x) {
    union { float f; unsigned u; } c; c.f = x;
    unsigned r = c.u + 0x7FFF + ((c.u >> 16) & 1);
    return (unsigned short)(r >> 16);
}

// ---------------------------------------------------------------------------
// fp32 -> bf16 conversion (weights), n divisible by 1024
// ---------------------------------------------------------------------------
__global__ __launch_bounds__(256) void cvt_kernel(
    const float* __restrict__ s, unsigned short* __restrict__ d)
{
    int i = blockIdx.x * 256 + threadIdx.x;
    float4 v = ((const float4*)s)[i];
    union { unsigned short u[4]; unsigned long long ll; } o;
    o.u[0] = f2bf(v.x); o.u[1] = f2bf(v.y); o.u[2] = f2bf(v.z); o.u[3] = f2bf(v.w);
    ((unsigned long long*)d)[i] = o.ll;
}

__global__ __launch_bounds__(256) void concat_bias(
    const float* __restrict__ bq, const float* __restrict__ bk,
    const float* __restrict__ bv, float* __restrict__ d)
{
    int i = blockIdx.x * 256 + threadIdx.x;
    if (i < 768) d[i] = bq[i];
    else if (i < 1536) d[i] = bk[i - 768];
    else d[i] = bv[i - 1536];
}

// ---------------------------------------------------------------------------
// LayerNorm: one block per row, bf16 output
// ---------------------------------------------------------------------------
__global__ __launch_bounds__(256) void ln_kernel(
    const float* __restrict__ x, const float* __restrict__ g,
    const float* __restrict__ b, unsigned short* __restrict__ z)
{
    int row = blockIdx.x;
    const float* xr = x + (size_t)row * D_MODEL;
    unsigned short* zr = z + (size_t)row * D_MODEL;
    int t = threadIdx.x;
    float loc[3];
    float s1 = 0.f, s2 = 0.f;
#pragma unroll
    for (int i = 0; i < 3; ++i) {
        float v = xr[t + 256 * i];
        loc[i] = v; s1 += v; s2 += v * v;
    }
#pragma unroll
    for (int off = 32; off > 0; off >>= 1) {
        s1 += __shfl_down(s1, off);
        s2 += __shfl_down(s2, off);
    }
    __shared__ float r1[4], r2[4];
    __shared__ float mu_s, is_s;
    int wave = t >> 6, lane = t & 63;
    if (lane == 0) { r1[wave] = s1; r2[wave] = s2; }
    __syncthreads();
    if (t == 0) {
        float a = r1[0] + r1[1] + r1[2] + r1[3];
        float c = r2[0] + r2[1] + r2[2] + r2[3];
        float mu = a * (1.f / D_MODEL);
        float var = c * (1.f / D_MODEL) - mu * mu;
        mu_s = mu; is_s = rsqrtf(var + EPS);
    }
    __syncthreads();
    float mu = mu_s, istd = is_s;
#pragma unroll
    for (int i = 0; i < 3; ++i) {
        int c = t + 256 * i;
        zr[c] = f2bf((loc[i] - mu) * istd * g[c] + b[c]);
    }
}

// ---------------------------------------------------------------------------
// bf16 MFMA GEMM: C[M,N] = A[M,K] * W[N,K]^T + bias, 128x128 tile, BK=32.
// MODE 0: bf16 out | 1: QKV (q,k -> qkv buf; v -> transposed vt) |
// MODE 2: f32 out + residual | 3: bf16 out + ELU
// LDS linear (global_load_lds), source pre-swizzled, reads swizzled:
// 64B rows, slot' = slot ^ ((row>>1)&3).
// ---------------------------------------------------------------------------
template <int MODE>
__global__ __launch_bounds__(256) void gemm_mfma(
    const unsigned short* __restrict__ A, const unsigned short* __restrict__ W,
    const float* __restrict__ bias, const float* __restrict__ res,
    void* __restrict__ outp, unsigned short* __restrict__ vt,
    int Ncols, int K)
{
    __shared__ short AsB[128 * 32];
    __shared__ short BsB[128 * 32];
    char* As = (char*)AsB;
    char* Bs = (char*)BsB;

    const int t = threadIdx.x;
    const int lane = t & 63, w = t >> 6;
    const int wr = w >> 1, wc = w & 1;
    const int row0 = blockIdx.y * 128, col0 = blockIdx.x * 128;
    const int fr = lane & 15, fg = lane >> 4;

    // staging: issue j covers LDS bytes [w*1024 + j*4096 + lane*16)
    int o0 = w * 1024 + lane * 16;
    int r0s = o0 >> 6,          sl0 = (o0 >> 4) & 3;
    int r1s = (o0 + 4096) >> 6, sl1 = ((o0 + 4096) >> 4) & 3;
    int ss0 = sl0 ^ ((r0s >> 1) & 3);
    int ss1 = sl1 ^ ((r1s >> 1) & 3);
    const unsigned short* Asrc0 = A + (size_t)(row0 + r0s) * K + ss0 * 8;
    const unsigned short* Asrc1 = A + (size_t)(row0 + r1s) * K + ss1 * 8;
    const unsigned short* Bsrc0 = W + (size_t)(col0 + r0s) * K + ss0 * 8;
    const unsigned short* Bsrc1 = W + (size_t)(col0 + r1s) * K + ss1 * 8;
    char* Ad0 = As + w * 1024; char* Ad1 = As + w * 1024 + 4096;
    char* Bd0 = Bs + w * 1024; char* Bd1 = Bs + w * 1024 + 4096;

    f32x4 acc[4][4] = {};

    for (int k0 = 0; k0 < K; k0 += 32) {
        __syncthreads();
        gload16(Asrc0 + k0, Ad0);
        gload16(Asrc1 + k0, Ad1);
        gload16(Bsrc0 + k0, Bd0);
        gload16(Bsrc1 + k0, Bd1);
        __syncthreads();
        short8 af[4], bfr[4];
#pragma unroll
        for (int m = 0; m < 4; ++m) {
            int r = wr * 64 + m * 16 + fr;
            af[m] = *(const short8*)(As + r * 64 + ((fg ^ ((r >> 1) & 3)) << 4));
        }
#pragma unroll
        for (int n = 0; n < 4; ++n) {
            int r = wc * 64 + n * 16 + fr;
            bfr[n] = *(const short8*)(Bs + r * 64 + ((fg ^ ((r >> 1) & 3)) << 4));
        }
#pragma unroll
        for (int m = 0; m < 4; ++m)
#pragma unroll
            for (int n = 0; n < 4; ++n)
                acc[m][n] = __builtin_amdgcn_mfma_f32_16x16x32_bf16(
                    af[m], bfr[n], acc[m][n], 0, 0, 0);
    }

#pragma unroll
    for (int m = 0; m < 4; ++m) {
        int rbase = row0 + wr * 64 + m * 16 + fg * 4;
#pragma unroll
        for (int n = 0; n < 4; ++n) {
            int col = col0 + wc * 64 + n * 16 + fr;
            float bv = bias[col];
#pragma unroll
            for (int r = 0; r < 4; ++r) {
                int row = rbase + r;
                float v = acc[m][n][r] + bv;
                if (MODE == 0) {
                    ((unsigned short*)outp)[(size_t)row * Ncols + col] = f2bf(v);
                } else if (MODE == 3) {
                    v = v > 0.f ? v : expm1f(v);
                    ((unsigned short*)outp)[(size_t)row * Ncols + col] = f2bf(v);
                } else if (MODE == 2) {
                    ((float*)outp)[(size_t)row * Ncols + col] =
                        v + res[(size_t)row * Ncols + col];
                } else { // QKV
                    if (col < 1536) {
                        ((unsigned short*)outp)[(size_t)row * QKV_N + col] = f2bf(v);
                    } else {
                        int cc = col - 1536;
                        int hh = cc >> 6, dk = cc & 63;
                        int s = row >> 1, bb = row & 1;
                        vt[(((size_t)(bb * N_HEADS + hh) * 64 + dk) << 11) + s] = f2bf(v);
                    }
                }
            }
        }
    }
}

// ---------------------------------------------------------------------------
// Flash attention, bf16 MFMA. Block = (64 q-rows, bh), 4 waves x 16 q-rows.
// Swapped QK^T: S'[key][q] = mfma(K, Q) -> softmax lane-local (q = lane&15).
// P -> per-wave swizzled LDS -> A-operand of PV. V pre-transposed in vt.
// 128B rows, slot' = slot ^ (row&7).
// ---------------------------------------------------------------------------
__global__ __launch_bounds__(256) void attn_mfma(
    const unsigned short* __restrict__ qkv, const unsigned short* __restrict__ vt,
    unsigned short* __restrict__ ctx)
{
    __shared__ short KsB[64 * 64];
    __shared__ short VtB[64 * 64];
    __shared__ short PsB[4][16 * 64];
    char* Ks = (char*)KsB;
    char* Vts = (char*)VtB;

    const int t = threadIdx.x, lane = t & 63, w = t >> 6;
    const int fr = lane & 15, fg = lane >> 4;
    const int qb = blockIdx.x, bh = blockIdx.y;
    const int b = bh / N_HEADS, h = bh % N_HEADS;

    // Q fragments (B-operand): lane holds q-col fr, dk = s*32 + fg*8
    short8 qf[2];
    {
        int srow = qb * 64 + w * 16 + fr;
        size_t tok = (size_t)srow * B_SZ + b;
#pragma unroll
        for (int s = 0; s < 2; ++s)
            qf[s] = *(const short8*)(qkv + tok * QKV_N + h * 64 + s * 32 + fg * 8);
    }

    float m_run = -1e30f, l_run = 0.f;
    f32x4 O[4] = {};

    int o0 = w * 1024 + lane * 16;
    int r0 = o0 >> 7,          sl0 = (o0 >> 4) & 7;
    int r1 = (o0 + 4096) >> 7, sl1 = ((o0 + 4096) >> 4) & 7;
    int ss0 = sl0 ^ (r0 & 7), ss1 = sl1 ^ (r1 & 7);
    const unsigned short* kbase = qkv + 768 + h * 64;
    const unsigned short* vtb = vt + (size_t)bh * 64 * S_LEN;
    char* Kd0 = Ks + w * 1024;  char* Kd1 = Ks + w * 1024 + 4096;
    char* Vd0 = Vts + w * 1024; char* Vd1 = Vts + w * 1024 + 4096;
    char* Pw = (char*)PsB[w];

    for (int kb = 0; kb < S_LEN / 64; ++kb) {
        __syncthreads();
        gload16(kbase + ((size_t)(kb * 64 + r0) * B_SZ + b) * QKV_N + ss0 * 8, Kd0);
        gload16(kbase + ((size_t)(kb * 64 + r1) * B_SZ + b) * QKV_N + ss1 * 8, Kd1);
        gload16(vtb + (size_t)r0 * S_LEN + kb * 64 + ss0 * 8, Vd0);
        gload16(vtb + (size_t)r1 * S_LEN + kb * 64 + ss1 * 8, Vd1);
        __syncthreads();

        // S'[key][q] = K . Q^T
        f32x4 sacc[4] = {};
#pragma unroll
        for (int f = 0; f < 4; ++f) {
            int r = f * 16 + fr;
#pragma unroll
            for (int s = 0; s < 2; ++s) {
                int slot = (s * 4 + fg) ^ (r & 7);
                short8 kf = *(const short8*)(Ks + r * 128 + slot * 16);
                sacc[f] = __builtin_amdgcn_mfma_f32_16x16x32_bf16(kf, qf[s], sacc[f], 0, 0, 0);
            }
        }

        // online softmax: lane owns q = fr, 16 key-values (keys f*16+fg*4+r)
        float p[16];
        float mx = -1e30f;
#pragma unroll
        for (int f = 0; f < 4; ++f)
#pragma unroll
            for (int r = 0; r < 4; ++r) {
                float vv = sacc[f][r] * SCALE;
                p[f * 4 + r] = vv;
                mx = fmaxf(mx, vv);
            }
        mx = fmaxf(mx, __shfl_xor(mx, 16));
        mx = fmaxf(mx, __shfl_xor(mx, 32));
        float mnew = fmaxf(m_run, mx);
        float alpha = __expf(m_run - mnew);
        float tsum = 0.f;
#pragma unroll
        for (int i = 0; i < 16; ++i) {
            float e = __expf(p[i] - mnew);
            p[i] = e; tsum += e;
        }
        tsum += __shfl_xor(tsum, 16);
        tsum += __shfl_xor(tsum, 32);
        l_run = l_run * alpha + tsum;
        m_run = mnew;
        float a0 = __shfl(alpha, fg * 4 + 0), a1 = __shfl(alpha, fg * 4 + 1);
        float a2 = __shfl(alpha, fg * 4 + 2), a3 = __shfl(alpha, fg * 4 + 3);
#pragma unroll
        for (int n = 0; n < 4; ++n) {
            O[n][0] *= a0; O[n][1] *= a1; O[n][2] *= a2; O[n][3] *= a3;
        }

        // P -> LDS (per-wave, swizzled): row q=fr, keys f*16+fg*4+{0..3}
#pragma unroll
        for (int f = 0; f < 4; ++f) {
            unsigned u0 = (unsigned)f2bf(p[f * 4 + 0]) | ((unsigned)f2bf(p[f * 4 + 1]) << 16);
            unsigned u1 = (unsigned)f2bf(p[f * 4 + 2]) | ((unsigned)f2bf(p[f * 4 + 3]) << 16);
            unsigned long long uu = (unsigned long long)u0 | ((unsigned long long)u1 << 32);
            int slot = (f * 2 + (fg >> 1)) ^ (fr & 7);
            *(unsigned long long*)(Pw + fr * 128 + slot * 16 + (fg & 1) * 8) = uu;
        }
        asm volatile("s_waitcnt lgkmcnt(0)" ::: "memory");
        __builtin_amdgcn_sched_barrier(0);

        // O[q][dk] += P[q][key] * V[key][dk]
#pragma unroll
        for (int s = 0; s < 2; ++s) {
            int pslot = (s * 4 + fg) ^ (fr & 7);
            short8 pf = *(const short8*)(Pw + fr * 128 + pslot * 16);
#pragma unroll
            for (int n = 0; n < 4; ++n) {
                int vrow = n * 16 + fr;
                int vslot = (s * 4 + fg) ^ (vrow & 7);
                short8 vf = *(const short8*)(Vts + vrow * 128 + vslot * 16);
                O[n] = __builtin_amdgcn_mfma_f32_16x16x32_bf16(pf, vf, O[n], 0, 0, 0);
            }
        }
    }

    float li0 = __shfl(l_run, fg * 4 + 0), li1 = __shfl(l_run, fg * 4 + 1);
    float li2 = __shfl(l_run, fg * 4 + 2), li3 = __shfl(l_run, fg * 4 + 3);
    float i0 = 1.f / li0, i1 = 1.f / li1, i2 = 1.f / li2, i3 = 1.f / li3;
    int srow = qb * 64 + w * 16 + fg * 4;
    size_t tok0 = (size_t)srow * B_SZ + b;
#pragma unroll
    for (int n = 0; n < 4; ++n) {
        int col = h * 64 + n * 16 + fr;
        ctx[(tok0 + 0) * D_MODEL + col] = f2bf(O[n][0] * i0);
        ctx[(tok0 + 2) * D_MODEL + col] = f2bf(O[n][1] * i1);
        ctx[(tok0 + 4) * D_MODEL + col] = f2bf(O[n][2] * i2);
        ctx[(tok0 + 6) * D_MODEL + col] = f2bf(O[n][3] * i3);
    }
}

// ---------------------------------------------------------------------------
extern "C" void kernel_launch(void* const* d_in, const int* in_sizes, int n_in,
                              void* d_out, int out_size, void* d_ws, size_t ws_size,
                              hipStream_t stream)
{
    (void)in_sizes; (void)n_in; (void)out_size; (void)ws_size;
    const float* x   = (const float*)d_in[0];
    const float* wq  = (const float*)d_in[1];
    const float* bq  = (const float*)d_in[2];
    const float* wk  = (const float*)d_in[3];
    const float* bk  = (const float*)d_in[4];
    const float* wv  = (const float*)d_in[5];
    const float* bv  = (const float*)d_in[6];
    const float* wo  = (const float*)d_in[7];
    const float* bo  = (const float*)d_in[8];
    const float* g1  = (const float*)d_in[9];
    const float* b1  = (const float*)d_in[10];
    const float* g2  = (const float*)d_in[11];
    const float* b2  = (const float*)d_in[12];
    const float* w1  = (const float*)d_in[13];
    const float* bb1 = (const float*)d_in[14];
    const float* w2  = (const float*)d_in[15];
    const float* bb2 = (const float*)d_in[16];
    float* out = (float*)d_out;

    // workspace layout (bytes)
    char* p = (char*)d_ws;
    unsigned short* z    = (unsigned short*)p;                 // 4096*768   (z1 / ctx / z2)
    p += (size_t)N_TOK * D_MODEL * 2;
    unsigned short* qkv  = (unsigned short*)p;                 // 4096*2304
    unsigned short* hbuf = (unsigned short*)p;                 // 4096*3072 overlays qkv+vt
    p += (size_t)N_TOK * QKV_N * 2;
    unsigned short* vtb  = (unsigned short*)p;                 // 24*64*2048
    p += (size_t)B_SZ * N_HEADS * 64 * S_LEN * 2;
    unsigned short* wqkvb = (unsigned short*)p; p += (size_t)QKV_N * D_MODEL * 2;
    unsigned short* wob   = (unsigned short*)p; p += (size_t)D_MODEL * D_MODEL * 2;
    unsigned short* w1b   = (unsigned short*)p; p += (size_t)DFF * D_MODEL * 2;
    unsigned short* w2b   = (unsigned short*)p; p += (size_t)D_MODEL * DFF * 2;
    float* biasqkv = (float*)p;

    dim3 blk(256);

    // weight conversions
    cvt_kernel<<<576, blk, 0, stream>>>(wq, wqkvb);
    cvt_kernel<<<576, blk, 0, stream>>>(wk, wqkvb + 768 * 768);
    cvt_kernel<<<576, blk, 0, stream>>>(wv, wqkvb + 2 * 768 * 768);
    cvt_kernel<<<576, blk, 0, stream>>>(wo, wob);
    cvt_kernel<<<2304, blk, 0, stream>>>(w1, w1b);
    cvt_kernel<<<2304, blk, 0, stream>>>(w2, w2b);
    concat_bias<<<9, blk, 0, stream>>>(bq, bk, bv, biasqkv);

    // z1 = LN(x)
    ln_kernel<<<N_TOK, blk, 0, stream>>>(x, g1, b1, z);
    // qkv = z1 @ Wqkv^T + b  (v transposed into vtb)
    gemm_mfma<1><<<dim3(QKV_N / 128, N_TOK / 128), blk, 0, stream>>>(
        z, wqkvb, biasqkv, nullptr, qkv, vtb, QKV_N, D_MODEL);
    // ctx = attention(q,k,v)  -> overwrites z
    attn_mfma<<<dim3(S_LEN / 64, B_SZ * N_HEADS), blk, 0, stream>>>(qkv, vtb, z);
    // out = x + ctx @ wo^T + bo
    gemm_mfma<2><<<dim3(D_MODEL / 128, N_TOK / 128), blk, 0, stream>>>(
        z, wob, bo, x, out, nullptr, D_MODEL, D_MODEL);
    // z2 = LN(out) -> z
    ln_kernel<<<N_TOK, blk, 0, stream>>>(out, g2, b2, z);
    // h = ELU(z2 @ w1^T + bb1)   (hbuf overlays dead qkv/vt space)
    gemm_mfma<3><<<dim3(DFF / 128, N_TOK / 128), blk, 0, stream>>>(
        z, w1b, bb1, nullptr, hbuf, nullptr, DFF, D_MODEL);
    // out += h @ w2^T + bb2
    gemm_mfma<2><<<dim3(D_MODEL / 128, N_TOK / 128), blk, 0, stream>>>(
        hbuf, w2b, bb2, out, out, nullptr, D_MODEL, DFF);
}

// Round 3
// 230.884 us; speedup vs baseline: 7.3430x; 1.1653x over previous
//
#include <hip/hip_runtime.h>
#include <hip/hip_bf16.h>
#include <math.h>

#define S_LEN   2048
#define B_SZ    2
#define D_MODEL 768
#define N_HEADS 12
#define DFF     3072
#define N_TOK   4096
#define EPS     1e-5f
#define SCALE   0.125f
#define QKV_N   2304

typedef __attribute__((ext_vector_type(8))) short short8;
typedef __attribute__((ext_vector_type(4))) float f32x4;
typedef unsigned long long u64;

__device__ __forceinline__ void gload16(const void* g, void* l) {
    __builtin_amdgcn_global_load_lds(
        (const __attribute__((address_space(1))) void*)g,
        (__attribute__((address_space(3))) void*)l, 16, 0, 0);
}
__device__ __forceinline__ unsigned short f2bf(float x) {
    union { float f; unsigned u; } c; c.f = x;
    unsigned r = c.u + 0x7FFF + ((c.u >> 16) & 1);
    return (unsigned short)(r >> 16);
}
__device__ __forceinline__ float bf2f(unsigned short u) {
    union { unsigned u; float f; } c; c.u = ((unsigned)u) << 16; return c.f;
}

// ---------------------------------------------------------------------------
__global__ __launch_bounds__(256) void cvt_kernel(
    const float* __restrict__ s, unsigned short* __restrict__ d)
{
    int i = blockIdx.x * 256 + threadIdx.x;
    float4 v = ((const float4*)s)[i];
    union { unsigned short u[4]; u64 ll; } o;
    o.u[0] = f2bf(v.x); o.u[1] = f2bf(v.y); o.u[2] = f2bf(v.z); o.u[3] = f2bf(v.w);
    ((u64*)d)[i] = o.ll;
}

__global__ __launch_bounds__(256) void concat_bias(
    const float* __restrict__ bq, const float* __restrict__ bk,
    const float* __restrict__ bv, float* __restrict__ d)
{
    int i = blockIdx.x * 256 + threadIdx.x;
    if (i < 768) d[i] = bq[i];
    else if (i < 1536) d[i] = bk[i - 768];
    else d[i] = bv[i - 1536];
}

// ---------------------------------------------------------------------------
__global__ __launch_bounds__(256) void ln_kernel(
    const float* __restrict__ x, const float* __restrict__ g,
    const float* __restrict__ b, unsigned short* __restrict__ z)
{
    int row = blockIdx.x;
    const float* xr = x + (size_t)row * D_MODEL;
    unsigned short* zr = z + (size_t)row * D_MODEL;
    int t = threadIdx.x;
    float loc[3];
    float s1 = 0.f, s2 = 0.f;
#pragma unroll
    for (int i = 0; i < 3; ++i) {
        float v = xr[t + 256 * i];
        loc[i] = v; s1 += v; s2 += v * v;
    }
#pragma unroll
    for (int off = 32; off > 0; off >>= 1) {
        s1 += __shfl_down(s1, off);
        s2 += __shfl_down(s2, off);
    }
    __shared__ float r1[4], r2[4];
    __shared__ float mu_s, is_s;
    int wave = t >> 6, lane = t & 63;
    if (lane == 0) { r1[wave] = s1; r2[wave] = s2; }
    __syncthreads();
    if (t == 0) {
        float a = r1[0] + r1[1] + r1[2] + r1[3];
        float c = r2[0] + r2[1] + r2[2] + r2[3];
        float mu = a * (1.f / D_MODEL);
        float var = c * (1.f / D_MODEL) - mu * mu;
        mu_s = mu; is_s = rsqrtf(var + EPS);
    }
    __syncthreads();
    float mu = mu_s, istd = is_s;
#pragma unroll
    for (int i = 0; i < 3; ++i) {
        int c = t + 256 * i;
        zr[c] = f2bf((loc[i] - mu) * istd * g[c] + b[c]);
    }
}

// ---------------------------------------------------------------------------
// bf16 MFMA GEMM, 128x128 tile, BK=32, 3-buffer 2-deep pipeline (counted vmcnt).
// MODE 1: QKV (q,k -> qkv; v -> transposed vt) | 2: f32 out + residual |
// MODE 3: bf16 out + ELU | 4: split-K bf16 partial (blockIdx.z selects half)
// ---------------------------------------------------------------------------
template <int MODE>
__global__ __launch_bounds__(256) void gemm_mfma(
    const unsigned short* __restrict__ A, const unsigned short* __restrict__ W,
    const float* __restrict__ bias, const float* __restrict__ res,
    void* __restrict__ outp, unsigned short* __restrict__ vt,
    int Ncols, int K, int lda, int ldw)
{
    __shared__ short AsB[3][128 * 32];
    __shared__ short BsB[3][128 * 32];

    const int t = threadIdx.x;
    const int lane = t & 63, w = t >> 6;
    const int wr = w >> 1, wc = w & 1;
    const int row0 = blockIdx.y * 128, col0 = blockIdx.x * 128;
    const int fr = lane & 15, fg = lane >> 4;

    if (MODE == 4) {
        A += (size_t)blockIdx.z * 1536;
        W += (size_t)blockIdx.z * 1536;
    }

    // staging: wave w covers LDS bytes [w*1024, w*1024+1024) and +4096
    int o0 = w * 1024 + lane * 16;
    int r0s = o0 >> 6,          sl0 = (o0 >> 4) & 3;
    int r1s = (o0 + 4096) >> 6, sl1 = ((o0 + 4096) >> 4) & 3;
    int ss0 = sl0 ^ ((r0s >> 1) & 3);
    int ss1 = sl1 ^ ((r1s >> 1) & 3);
    const unsigned short* Asrc0 = A + (size_t)(row0 + r0s) * lda + ss0 * 8;
    const unsigned short* Asrc1 = A + (size_t)(row0 + r1s) * lda + ss1 * 8;
    const unsigned short* Bsrc0 = W + (size_t)(col0 + r0s) * ldw + ss0 * 8;
    const unsigned short* Bsrc1 = W + (size_t)(col0 + r1s) * ldw + ss1 * 8;
    const int od0 = w * 1024, od1 = w * 1024 + 4096;

    f32x4 acc[4][4] = {};
    const int nt = K / 32;

    auto stage = [&](int c, int k0) {
        gload16(Asrc0 + k0, (char*)AsB[c] + od0);
        gload16(Asrc1 + k0, (char*)AsB[c] + od1);
        gload16(Bsrc0 + k0, (char*)BsB[c] + od0);
        gload16(Bsrc1 + k0, (char*)BsB[c] + od1);
    };

    stage(0, 0);
    stage(1, 32);

    for (int tt = 0; tt < nt; ++tt) {
        // wait own tile-t loads (4 newest belong to t+1), then all-wave barrier
        if (tt + 1 < nt)
            asm volatile("s_waitcnt vmcnt(4)\n\ts_barrier" ::: "memory");
        else
            asm volatile("s_waitcnt vmcnt(0)\n\ts_barrier" ::: "memory");
        if (tt + 2 < nt) stage((tt + 2) % 3, (tt + 2) * 32);

        const char* As = (const char*)AsB[tt % 3];
        const char* Bs = (const char*)BsB[tt % 3];
        short8 af[4], bfr[4];
#pragma unroll
        for (int m = 0; m < 4; ++m) {
            int r = wr * 64 + m * 16 + fr;
            af[m] = *(const short8*)(As + r * 64 + ((fg ^ ((r >> 1) & 3)) << 4));
        }
#pragma unroll
        for (int n = 0; n < 4; ++n) {
            int r = wc * 64 + n * 16 + fr;
            bfr[n] = *(const short8*)(Bs + r * 64 + ((fg ^ ((r >> 1) & 3)) << 4));
        }
#pragma unroll
        for (int m = 0; m < 4; ++m)
#pragma unroll
            for (int n = 0; n < 4; ++n)
                acc[m][n] = __builtin_amdgcn_mfma_f32_16x16x32_bf16(
                    af[m], bfr[n], acc[m][n], 0, 0, 0);
    }

    unsigned short* pout16 = nullptr;
    if (MODE == 4) pout16 = blockIdx.z ? vt : (unsigned short*)outp;

#pragma unroll
    for (int m = 0; m < 4; ++m) {
        int rbase = row0 + wr * 64 + m * 16 + fg * 4;
#pragma unroll
        for (int n = 0; n < 4; ++n) {
            int col = col0 + wc * 64 + n * 16 + fr;
            float bv = (MODE == 4) ? 0.f : bias[col];
            if (MODE == 1 && col >= 1536) {
                // V columns -> transposed vt[bh][dk][s], packed dword stores
                int cc = col - 1536, hh = cc >> 6, dk = cc & 63;
                int s_a = rbase >> 1;   // rbase multiple of 4 -> s_a even
                float v0 = acc[m][n][0] + bv, v1 = acc[m][n][1] + bv;
                float v2 = acc[m][n][2] + bv, v3 = acc[m][n][3] + bv;
                unsigned lo = (unsigned)f2bf(v0) | ((unsigned)f2bf(v2) << 16);
                unsigned hi = (unsigned)f2bf(v1) | ((unsigned)f2bf(v3) << 16);
                *(unsigned*)&vt[((size_t)hh * 64 + dk) * 2048 + s_a] = lo;
                *(unsigned*)&vt[((size_t)(N_HEADS + hh) * 64 + dk) * 2048 + s_a] = hi;
            } else {
#pragma unroll
                for (int r = 0; r < 4; ++r) {
                    int row = rbase + r;
                    float v = acc[m][n][r] + bv;
                    if (MODE == 3) {
                        v = v > 0.f ? v : expm1f(v);
                        ((unsigned short*)outp)[(size_t)row * Ncols + col] = f2bf(v);
                    } else if (MODE == 2) {
                        ((float*)outp)[(size_t)row * Ncols + col] =
                            v + res[(size_t)row * Ncols + col];
                    } else if (MODE == 4) {
                        pout16[(size_t)row * 768 + col] = f2bf(v);
                    } else {  // MODE 1, q/k
                        ((unsigned short*)outp)[(size_t)row * QKV_N + col] = f2bf(v);
                    }
                }
            }
        }
    }
}

// ---------------------------------------------------------------------------
// out[i] += bf(p0[i]) + bf(p1[i]) + bias[col]   (out holds residual x1)
// ---------------------------------------------------------------------------
__global__ __launch_bounds__(256) void reduce_ffn2(
    const unsigned short* __restrict__ p0, const unsigned short* __restrict__ p1,
    const float* __restrict__ bias, float* __restrict__ out)
{
    int i = blockIdx.x * 256 + threadIdx.x;     // group of 4 elems
    int col4 = i % (D_MODEL / 4);
    u64 a = ((const u64*)p0)[i];
    u64 c = ((const u64*)p1)[i];
    float4 o = ((float4*)out)[i];
    float4 bb = ((const float4*)bias)[col4];
    o.x += bf2f((unsigned short)a)         + bf2f((unsigned short)c)         + bb.x;
    o.y += bf2f((unsigned short)(a >> 16)) + bf2f((unsigned short)(c >> 16)) + bb.y;
    o.z += bf2f((unsigned short)(a >> 32)) + bf2f((unsigned short)(c >> 32)) + bb.z;
    o.w += bf2f((unsigned short)(a >> 48)) + bf2f((unsigned short)(c >> 48)) + bb.w;
    ((float4*)out)[i] = o;
}

// ---------------------------------------------------------------------------
// Flash attention, bf16 MFMA, K/V double-buffered (1-deep prefetch).
// ---------------------------------------------------------------------------
__global__ __launch_bounds__(256) void attn_mfma(
    const unsigned short* __restrict__ qkv, const unsigned short* __restrict__ vt,
    unsigned short* __restrict__ ctx)
{
    __shared__ short KsB[2][64 * 64];
    __shared__ short VtB[2][64 * 64];
    __shared__ short PsB[4][16 * 64];

    const int t = threadIdx.x, lane = t & 63, w = t >> 6;
    const int fr = lane & 15, fg = lane >> 4;
    const int qb = blockIdx.x, bh = blockIdx.y;
    const int b = bh / N_HEADS, h = bh % N_HEADS;

    short8 qf[2];
    {
        int srow = qb * 64 + w * 16 + fr;
        size_t tok = (size_t)srow * B_SZ + b;
#pragma unroll
        for (int s = 0; s < 2; ++s)
            qf[s] = *(const short8*)(qkv + tok * QKV_N + h * 64 + s * 32 + fg * 8);
    }

    float m_run = -1e30f, l_run = 0.f;
    f32x4 O[4] = {};

    int o0 = w * 1024 + lane * 16;
    int r0 = o0 >> 7,          sl0 = (o0 >> 4) & 7;
    int r1 = (o0 + 4096) >> 7, sl1 = ((o0 + 4096) >> 4) & 7;
    int ss0 = sl0 ^ (r0 & 7), ss1 = sl1 ^ (r1 & 7);
    const unsigned short* kbase = qkv + 768 + h * 64;
    const unsigned short* vtb = vt + (size_t)bh * 64 * S_LEN;
    const int od0 = w * 1024, od1 = w * 1024 + 4096;
    char* Pw = (char*)PsB[w];

    auto stageKV = [&](int c, int kb) {
        gload16(kbase + ((size_t)(kb * 64 + r0) * B_SZ + b) * QKV_N + ss0 * 8, (char*)KsB[c] + od0);
        gload16(kbase + ((size_t)(kb * 64 + r1) * B_SZ + b) * QKV_N + ss1 * 8, (char*)KsB[c] + od1);
        gload16(vtb + (size_t)r0 * S_LEN + kb * 64 + ss0 * 8, (char*)VtB[c] + od0);
        gload16(vtb + (size_t)r1 * S_LEN + kb * 64 + ss1 * 8, (char*)VtB[c] + od1);
    };

    stageKV(0, 0);

    for (int kb = 0; kb < S_LEN / 64; ++kb) {
        __syncthreads();                         // drains staged loads for kb
        if (kb + 1 < S_LEN / 64) stageKV((kb + 1) & 1, kb + 1);
        const char* Ks  = (const char*)KsB[kb & 1];
        const char* Vts = (const char*)VtB[kb & 1];

        // S'[key][q] = K . Q^T
        f32x4 sacc[4] = {};
#pragma unroll
        for (int f = 0; f < 4; ++f) {
            int r = f * 16 + fr;
#pragma unroll
            for (int s = 0; s < 2; ++s) {
                int slot = (s * 4 + fg) ^ (r & 7);
                short8 kf = *(const short8*)(Ks + r * 128 + slot * 16);
                sacc[f] = __builtin_amdgcn_mfma_f32_16x16x32_bf16(kf, qf[s], sacc[f], 0, 0, 0);
            }
        }

        // online softmax: lane owns q = fr
        float p[16];
        float mx = -1e30f;
#pragma unroll
        for (int f = 0; f < 4; ++f)
#pragma unroll
            for (int r = 0; r < 4; ++r) {
                float vv = sacc[f][r] * SCALE;
                p[f * 4 + r] = vv;
                mx = fmaxf(mx, vv);
            }
        mx = fmaxf(mx, __shfl_xor(mx, 16));
        mx = fmaxf(mx, __shfl_xor(mx, 32));
        float mnew = fmaxf(m_run, mx);
        float alpha = __expf(m_run - mnew);
        float tsum = 0.f;
#pragma unroll
        for (int i = 0; i < 16; ++i) {
            float e = __expf(p[i] - mnew);
            p[i] = e; tsum += e;
        }
        tsum += __shfl_xor(tsum, 16);
        tsum += __shfl_xor(tsum, 32);
        l_run = l_run * alpha + tsum;
        m_run = mnew;
        float a0 = __shfl(alpha, fg * 4 + 0), a1 = __shfl(alpha, fg * 4 + 1);
        float a2 = __shfl(alpha, fg * 4 + 2), a3 = __shfl(alpha, fg * 4 + 3);
#pragma unroll
        for (int n = 0; n < 4; ++n) {
            O[n][0] *= a0; O[n][1] *= a1; O[n][2] *= a2; O[n][3] *= a3;
        }

        // P -> per-wave swizzled LDS
#pragma unroll
        for (int f = 0; f < 4; ++f) {
            unsigned u0 = (unsigned)f2bf(p[f * 4 + 0]) | ((unsigned)f2bf(p[f * 4 + 1]) << 16);
            unsigned u1 = (unsigned)f2bf(p[f * 4 + 2]) | ((unsigned)f2bf(p[f * 4 + 3]) << 16);
            u64 uu = (u64)u0 | ((u64)u1 << 32);
            int slot = (f * 2 + (fg >> 1)) ^ (fr & 7);
            *(u64*)(Pw + fr * 128 + slot * 16 + (fg & 1) * 8) = uu;
        }
        asm volatile("s_waitcnt lgkmcnt(0)" ::: "memory");
        __builtin_amdgcn_sched_barrier(0);

        // O[q][dk] += P[q][key] * V[key][dk]
#pragma unroll
        for (int s = 0; s < 2; ++s) {
            int pslot = (s * 4 + fg) ^ (fr & 7);
            short8 pf = *(const short8*)(Pw + fr * 128 + pslot * 16);
#pragma unroll
            for (int n = 0; n < 4; ++n) {
                int vrow = n * 16 + fr;
                int vslot = (s * 4 + fg) ^ (vrow & 7);
                short8 vf = *(const short8*)(Vts + vrow * 128 + vslot * 16);
                O[n] = __builtin_amdgcn_mfma_f32_16x16x32_bf16(pf, vf, O[n], 0, 0, 0);
            }
        }
    }

    float li0 = __shfl(l_run, fg * 4 + 0), li1 = __shfl(l_run, fg * 4 + 1);
    float li2 = __shfl(l_run, fg * 4 + 2), li3 = __shfl(l_run, fg * 4 + 3);
    float i0 = 1.f / li0, i1 = 1.f / li1, i2 = 1.f / li2, i3 = 1.f / li3;
    int srow = qb * 64 + w * 16 + fg * 4;
    size_t tok0 = (size_t)srow * B_SZ + b;
#pragma unroll
    for (int n = 0; n < 4; ++n) {
        int col = h * 64 + n * 16 + fr;
        ctx[(tok0 + 0) * D_MODEL + col] = f2bf(O[n][0] * i0);
        ctx[(tok0 + 2) * D_MODEL + col] = f2bf(O[n][1] * i1);
        ctx[(tok0 + 4) * D_MODEL + col] = f2bf(O[n][2] * i2);
        ctx[(tok0 + 6) * D_MODEL + col] = f2bf(O[n][3] * i3);
    }
}

// ---------------------------------------------------------------------------
extern "C" void kernel_launch(void* const* d_in, const int* in_sizes, int n_in,
                              void* d_out, int out_size, void* d_ws, size_t ws_size,
                              hipStream_t stream)
{
    (void)in_sizes; (void)n_in; (void)out_size; (void)ws_size;
    const float* x   = (const float*)d_in[0];
    const float* wq  = (const float*)d_in[1];
    const float* bq  = (const float*)d_in[2];
    const float* wk  = (const float*)d_in[3];
    const float* bk  = (const float*)d_in[4];
    const float* wv  = (const float*)d_in[5];
    const float* bv  = (const float*)d_in[6];
    const float* wo  = (const float*)d_in[7];
    const float* bo  = (const float*)d_in[8];
    const float* g1  = (const float*)d_in[9];
    const float* b1  = (const float*)d_in[10];
    const float* g2  = (const float*)d_in[11];
    const float* b2  = (const float*)d_in[12];
    const float* w1  = (const float*)d_in[13];
    const float* bb1 = (const float*)d_in[14];
    const float* w2  = (const float*)d_in[15];
    const float* bb2 = (const float*)d_in[16];
    float* out = (float*)d_out;

    // workspace layout
    char* p = (char*)d_ws;
    unsigned short* z    = (unsigned short*)p;                 // z1 / ctx / z2 ; FFN2 part0
    p += (size_t)N_TOK * D_MODEL * 2;
    unsigned short* qkv  = (unsigned short*)p;                 // qkv ; later hbuf
    unsigned short* hbuf = (unsigned short*)p;                 // 4096*3072 overlays qkv+vt
    p += (size_t)N_TOK * QKV_N * 2;
    unsigned short* vtb  = (unsigned short*)p;
    p += (size_t)B_SZ * N_HEADS * 64 * S_LEN * 2;
    unsigned short* wqkvb = (unsigned short*)p;                // FFN2 part1 overlays wqkv..w1
    p += (size_t)QKV_N * D_MODEL * 2;
    unsigned short* wob   = (unsigned short*)p; p += (size_t)D_MODEL * D_MODEL * 2;
    unsigned short* w1b   = (unsigned short*)p; p += (size_t)DFF * D_MODEL * 2;
    unsigned short* w2b   = (unsigned short*)p; p += (size_t)D_MODEL * DFF * 2;
    float* biasqkv = (float*)p;
    unsigned short* part0 = z;
    unsigned short* part1 = wqkvb;

    dim3 blk(256);

    cvt_kernel<<<576, blk, 0, stream>>>(wq, wqkvb);
    cvt_kernel<<<576, blk, 0, stream>>>(wk, wqkvb + 768 * 768);
    cvt_kernel<<<576, blk, 0, stream>>>(wv, wqkvb + 2 * 768 * 768);
    cvt_kernel<<<576, blk, 0, stream>>>(wo, wob);
    cvt_kernel<<<2304, blk, 0, stream>>>(w1, w1b);
    cvt_kernel<<<2304, blk, 0, stream>>>(w2, w2b);
    concat_bias<<<9, blk, 0, stream>>>(bq, bk, bv, biasqkv);

    // z1 = LN(x)
    ln_kernel<<<N_TOK, blk, 0, stream>>>(x, g1, b1, z);
    // qkv = z1 @ Wqkv^T + b  (v -> vtb transposed)
    gemm_mfma<1><<<dim3(QKV_N / 128, N_TOK / 128), blk, 0, stream>>>(
        z, wqkvb, biasqkv, nullptr, qkv, vtb, QKV_N, D_MODEL, D_MODEL, D_MODEL);
    // ctx = attention -> z
    attn_mfma<<<dim3(S_LEN / 64, B_SZ * N_HEADS), blk, 0, stream>>>(qkv, vtb, z);
    // out = x + ctx @ wo^T + bo
    gemm_mfma<2><<<dim3(D_MODEL / 128, N_TOK / 128), blk, 0, stream>>>(
        z, wob, bo, x, out, nullptr, D_MODEL, D_MODEL, D_MODEL, D_MODEL);
    // z2 = LN(out)
    ln_kernel<<<N_TOK, blk, 0, stream>>>(out, g2, b2, z);
    // h = ELU(z2 @ w1^T + bb1)
    gemm_mfma<3><<<dim3(DFF / 128, N_TOK / 128), blk, 0, stream>>>(
        z, w1b, bb1, nullptr, hbuf, nullptr, DFF, D_MODEL, D_MODEL, D_MODEL);
    // FFN2 split-K=2 partials (z region dead now; weight regions wqkv..w1 dead)
    gemm_mfma<4><<<dim3(D_MODEL / 128, N_TOK / 128, 2), blk, 0, stream>>>(
        hbuf, w2b, nullptr, nullptr, part0, part1, D_MODEL, 1536, DFF, DFF);
    // out += part0 + part1 + bb2
    reduce_ffn2<<<N_TOK * D_MODEL / 4 / 256, blk, 0, stream>>>(part0, part1, bb2, out);
}

// Round 4
// 207.739 us; speedup vs baseline: 8.1611x; 1.1114x over previous
//
#include <hip/hip_runtime.h>
#include <hip/hip_bf16.h>
#include <math.h>

#define S_LEN   2048
#define B_SZ    2
#define D_MODEL 768
#define N_HEADS 12
#define DFF     3072
#define N_TOK   4096
#define EPS     1e-5f
#define QKV_N   2304
#define SLOG2E  0.18033688011112042f   // 0.125 * log2(e)

typedef __attribute__((ext_vector_type(8))) short short8;
typedef __attribute__((ext_vector_type(4))) float f32x4;
typedef unsigned long long u64;
typedef unsigned short u16;
typedef unsigned u32;

__device__ __forceinline__ void gload16(const void* g, void* l) {
    __builtin_amdgcn_global_load_lds(
        (const __attribute__((address_space(1))) void*)g,
        (__attribute__((address_space(3))) void*)l, 16, 0, 0);
}
__device__ __forceinline__ u16 f2bf(float x) {
    union { float f; unsigned u; } c; c.f = x;
    unsigned r = c.u + 0x7FFF + ((c.u >> 16) & 1);
    return (u16)(r >> 16);
}
__device__ __forceinline__ float bf2f(u16 u) {
    union { unsigned u; float f; } c; c.u = ((unsigned)u) << 16; return c.f;
}
__device__ __forceinline__ float fast_exp2(float x) {
    float r; asm("v_exp_f32 %0, %1" : "=v"(r) : "v"(x)); return r;
}

// ---------------------------------------------------------------------------
// All six weight matrices -> bf16 in one launch (dsts contiguous at dst base)
// order: wq | wk | wv | wo | w1 | w2   (float4 granularity)
// ---------------------------------------------------------------------------
__global__ __launch_bounds__(256) void cvt_all(
    const float* __restrict__ wq, const float* __restrict__ wk,
    const float* __restrict__ wv, const float* __restrict__ wo,
    const float* __restrict__ w1, const float* __restrict__ w2,
    u16* __restrict__ dst)
{
    const int W = 147456;  // 768*768/4
    int i = blockIdx.x * 256 + threadIdx.x;
    const float* src; int off;
    if      (i <     W) { src = wq; off = 0;     }
    else if (i < 2 * W) { src = wk; off = W;     }
    else if (i < 3 * W) { src = wv; off = 2 * W; }
    else if (i < 4 * W) { src = wo; off = 3 * W; }
    else if (i < 8 * W) { src = w1; off = 4 * W; }
    else                { src = w2; off = 8 * W; }
    float4 v = ((const float4*)src)[i - off];
    union { u16 u[4]; u64 ll; } o;
    o.u[0] = f2bf(v.x); o.u[1] = f2bf(v.y); o.u[2] = f2bf(v.z); o.u[3] = f2bf(v.w);
    ((u64*)dst)[i] = o.ll;
}

__global__ __launch_bounds__(256) void concat_bias(
    const float* __restrict__ bq, const float* __restrict__ bk,
    const float* __restrict__ bv, float* __restrict__ d)
{
    int i = blockIdx.x * 256 + threadIdx.x;
    if (i < 768) d[i] = bq[i];
    else if (i < 1536) d[i] = bk[i - 768];
    else d[i] = bv[i - 1536];
}

// ---------------------------------------------------------------------------
__global__ __launch_bounds__(256) void ln_kernel(
    const float* __restrict__ x, const float* __restrict__ g,
    const float* __restrict__ b, u16* __restrict__ z)
{
    int row = blockIdx.x;
    const float* xr = x + (size_t)row * D_MODEL;
    u16* zr = z + (size_t)row * D_MODEL;
    int t = threadIdx.x;
    float loc[3];
    float s1 = 0.f, s2 = 0.f;
#pragma unroll
    for (int i = 0; i < 3; ++i) {
        float v = xr[t + 256 * i];
        loc[i] = v; s1 += v; s2 += v * v;
    }
#pragma unroll
    for (int off = 32; off > 0; off >>= 1) {
        s1 += __shfl_down(s1, off);
        s2 += __shfl_down(s2, off);
    }
    __shared__ float r1[4], r2[4];
    __shared__ float mu_s, is_s;
    int wave = t >> 6, lane = t & 63;
    if (lane == 0) { r1[wave] = s1; r2[wave] = s2; }
    __syncthreads();
    if (t == 0) {
        float a = r1[0] + r1[1] + r1[2] + r1[3];
        float c = r2[0] + r2[1] + r2[2] + r2[3];
        float mu = a * (1.f / D_MODEL);
        float var = c * (1.f / D_MODEL) - mu * mu;
        mu_s = mu; is_s = rsqrtf(var + EPS);
    }
    __syncthreads();
    float mu = mu_s, istd = is_s;
#pragma unroll
    for (int i = 0; i < 3; ++i) {
        int c = t + 256 * i;
        zr[c] = f2bf((loc[i] - mu) * istd * g[c] + b[c]);
    }
}

// ---------------------------------------------------------------------------
// x1 = x + bf(p0) + bf(p1) + bres ; out fp32 x1 ; z = bf16 LN(x1, g, b)
// ---------------------------------------------------------------------------
__global__ __launch_bounds__(256) void ln_fuse(
    const float* __restrict__ x, const u16* __restrict__ p0,
    const u16* __restrict__ p1, const float* __restrict__ bres,
    const float* __restrict__ g, const float* __restrict__ b,
    float* __restrict__ xout, u16* __restrict__ z)
{
    int row = blockIdx.x;
    const float* xr = x + (size_t)row * D_MODEL;
    const u16* p0r = p0 + (size_t)row * D_MODEL;
    const u16* p1r = p1 + (size_t)row * D_MODEL;
    int t = threadIdx.x;
    float loc[3];
    float s1 = 0.f, s2 = 0.f;
#pragma unroll
    for (int i = 0; i < 3; ++i) {
        int c = t + 256 * i;
        float v = xr[c] + bf2f(p0r[c]) + bf2f(p1r[c]) + bres[c];
        loc[i] = v; s1 += v; s2 += v * v;
    }
#pragma unroll
    for (int off = 32; off > 0; off >>= 1) {
        s1 += __shfl_down(s1, off);
        s2 += __shfl_down(s2, off);
    }
    __shared__ float r1[4], r2[4];
    __shared__ float mu_s, is_s;
    int wave = t >> 6, lane = t & 63;
    if (lane == 0) { r1[wave] = s1; r2[wave] = s2; }
    __syncthreads();
    if (t == 0) {
        float a = r1[0] + r1[1] + r1[2] + r1[3];
        float c = r2[0] + r2[1] + r2[2] + r2[3];
        float mu = a * (1.f / D_MODEL);
        float var = c * (1.f / D_MODEL) - mu * mu;
        mu_s = mu; is_s = rsqrtf(var + EPS);
    }
    __syncthreads();
    float mu = mu_s, istd = is_s;
    float* xo = xout + (size_t)row * D_MODEL;
    u16* zr = z + (size_t)row * D_MODEL;
#pragma unroll
    for (int i = 0; i < 3; ++i) {
        int c = t + 256 * i;
        xo[c] = loc[i];
        zr[c] = f2bf((loc[i] - mu) * istd * g[c] + b[c]);
    }
}

// ---------------------------------------------------------------------------
// bf16 MFMA GEMM, 128x128 tile, BK=32, 3-buffer 2-deep pipeline (counted vmcnt).
// MODE 1: QKV (q scaled by SLOG2E; q,k -> qkv; v -> transposed vt)
// MODE 3: bf16 out + ELU | MODE 4: split-K bf16 partial (z picks outp/vt)
// ---------------------------------------------------------------------------
template <int MODE>
__global__ __launch_bounds__(256) void gemm_mfma(
    const u16* __restrict__ A, const u16* __restrict__ W,
    const float* __restrict__ bias, void* __restrict__ outp,
    u16* __restrict__ vt, int Ncols, int K, int lda, int ldw, int koff)
{
    __shared__ short AsB[3][128 * 32];
    __shared__ short BsB[3][128 * 32];

    const int t = threadIdx.x;
    const int lane = t & 63, w = t >> 6;
    const int wr = w >> 1, wc = w & 1;
    const int row0 = blockIdx.y * 128, col0 = blockIdx.x * 128;
    const int fr = lane & 15, fg = lane >> 4;

    if (MODE == 4) {
        A += (size_t)blockIdx.z * koff;
        W += (size_t)blockIdx.z * koff;
    }

    int o0 = w * 1024 + lane * 16;
    int r0s = o0 >> 6,          sl0 = (o0 >> 4) & 3;
    int r1s = (o0 + 4096) >> 6, sl1 = ((o0 + 4096) >> 4) & 3;
    int ss0 = sl0 ^ ((r0s >> 1) & 3);
    int ss1 = sl1 ^ ((r1s >> 1) & 3);
    const u16* Asrc0 = A + (size_t)(row0 + r0s) * lda + ss0 * 8;
    const u16* Asrc1 = A + (size_t)(row0 + r1s) * lda + ss1 * 8;
    const u16* Bsrc0 = W + (size_t)(col0 + r0s) * ldw + ss0 * 8;
    const u16* Bsrc1 = W + (size_t)(col0 + r1s) * ldw + ss1 * 8;
    const int od0 = w * 1024, od1 = w * 1024 + 4096;

    f32x4 acc[4][4] = {};
    const int nt = K / 32;

    auto stage = [&](int c, int k0) {
        gload16(Asrc0 + k0, (char*)AsB[c] + od0);
        gload16(Asrc1 + k0, (char*)AsB[c] + od1);
        gload16(Bsrc0 + k0, (char*)BsB[c] + od0);
        gload16(Bsrc1 + k0, (char*)BsB[c] + od1);
    };

    stage(0, 0);
    stage(1, 32);

    for (int tt = 0; tt < nt; ++tt) {
        if (tt + 1 < nt)
            asm volatile("s_waitcnt vmcnt(4)\n\ts_barrier" ::: "memory");
        else
            asm volatile("s_waitcnt vmcnt(0)\n\ts_barrier" ::: "memory");
        if (tt + 2 < nt) stage((tt + 2) % 3, (tt + 2) * 32);

        const char* As = (const char*)AsB[tt % 3];
        const char* Bs = (const char*)BsB[tt % 3];
        short8 af[4], bfr[4];
#pragma unroll
        for (int m = 0; m < 4; ++m) {
            int r = wr * 64 + m * 16 + fr;
            af[m] = *(const short8*)(As + r * 64 + ((fg ^ ((r >> 1) & 3)) << 4));
        }
#pragma unroll
        for (int n = 0; n < 4; ++n) {
            int r = wc * 64 + n * 16 + fr;
            bfr[n] = *(const short8*)(Bs + r * 64 + ((fg ^ ((r >> 1) & 3)) << 4));
        }
#pragma unroll
        for (int m = 0; m < 4; ++m)
#pragma unroll
            for (int n = 0; n < 4; ++n)
                acc[m][n] = __builtin_amdgcn_mfma_f32_16x16x32_bf16(
                    af[m], bfr[n], acc[m][n], 0, 0, 0);
    }

    u16* pout16 = nullptr;
    if (MODE == 4) pout16 = blockIdx.z ? vt : (u16*)outp;

#pragma unroll
    for (int m = 0; m < 4; ++m) {
        int rbase = row0 + wr * 64 + m * 16 + fg * 4;
#pragma unroll
        for (int n = 0; n < 4; ++n) {
            int col = col0 + wc * 64 + n * 16 + fr;
            float bv = (MODE == 4) ? 0.f : bias[col];
            if (MODE == 1 && col >= 1536) {
                int cc = col - 1536, hh = cc >> 6, dk = cc & 63;
                int s_a = rbase >> 1;
                float v0 = acc[m][n][0] + bv, v1 = acc[m][n][1] + bv;
                float v2 = acc[m][n][2] + bv, v3 = acc[m][n][3] + bv;
                unsigned lo = (unsigned)f2bf(v0) | ((unsigned)f2bf(v2) << 16);
                unsigned hi = (unsigned)f2bf(v1) | ((unsigned)f2bf(v3) << 16);
                *(unsigned*)&vt[((size_t)hh * 64 + dk) * 2048 + s_a] = lo;
                *(unsigned*)&vt[((size_t)(N_HEADS + hh) * 64 + dk) * 2048 + s_a] = hi;
            } else {
#pragma unroll
                for (int r = 0; r < 4; ++r) {
                    int row = rbase + r;
                    float v = acc[m][n][r] + bv;
                    if (MODE == 3) {
                        v = v > 0.f ? v : expm1f(v);
                        ((u16*)outp)[(size_t)row * Ncols + col] = f2bf(v);
                    } else if (MODE == 4) {
                        pout16[(size_t)row * 768 + col] = f2bf(v);
                    } else {  // MODE 1, q/k
                        if (col < 768) v *= SLOG2E;   // fold softmax scale+log2e into Q
                        ((u16*)outp)[(size_t)row * QKV_N + col] = f2bf(v);
                    }
                }
            }
        }
    }
}

// ---------------------------------------------------------------------------
// out = res + bf(p0) + bf(p1) + bias   (res may alias out)
// ---------------------------------------------------------------------------
__global__ __launch_bounds__(256) void reduce_add(
    const u16* __restrict__ p0, const u16* __restrict__ p1,
    const float* __restrict__ bias, const float* __restrict__ res,
    float* __restrict__ out)
{
    int i = blockIdx.x * 256 + threadIdx.x;
    int col4 = i % (D_MODEL / 4);
    u64 a = ((const u64*)p0)[i];
    u64 c = ((const u64*)p1)[i];
    float4 o = ((const float4*)res)[i];
    float4 bb = ((const float4*)bias)[col4];
    o.x += bf2f((u16)a)         + bf2f((u16)c)         + bb.x;
    o.y += bf2f((u16)(a >> 16)) + bf2f((u16)(c >> 16)) + bb.y;
    o.z += bf2f((u16)(a >> 32)) + bf2f((u16)(c >> 32)) + bb.z;
    o.w += bf2f((u16)(a >> 48)) + bf2f((u16)(c >> 48)) + bb.w;
    ((float4*)out)[i] = o;
}

// ---------------------------------------------------------------------------
// Flash attention, bf16 MFMA, K/V double-buffered. Scores arrive in exp2
// domain (Q pre-scaled by SLOG2E). Defer-max rescale (THR=8 in log2 units).
// ---------------------------------------------------------------------------
__global__ __launch_bounds__(256) void attn_mfma(
    const u16* __restrict__ qkv, const u16* __restrict__ vt,
    u16* __restrict__ ctx)
{
    __shared__ short KsB[2][64 * 64];
    __shared__ short VtB[2][64 * 64];
    __shared__ short PsB[4][16 * 64];

    const int t = threadIdx.x, lane = t & 63, w = t >> 6;
    const int fr = lane & 15, fg = lane >> 4;
    const int fg4 = fg * 4;
    const int qb = blockIdx.x, bh = blockIdx.y;
    const int b = bh / N_HEADS, h = bh % N_HEADS;

    short8 qf[2];
    {
        int srow = qb * 64 + w * 16 + fr;
        size_t tok = (size_t)srow * B_SZ + b;
#pragma unroll
        for (int s = 0; s < 2; ++s)
            qf[s] = *(const short8*)(qkv + tok * QKV_N + h * 64 + s * 32 + fg * 8);
    }

    float m2 = -1e30f, l_run = 0.f;
    f32x4 O[4] = {};

    int o0 = w * 1024 + lane * 16;
    int r0 = o0 >> 7,          sl0 = (o0 >> 4) & 7;
    int r1 = (o0 + 4096) >> 7, sl1 = ((o0 + 4096) >> 4) & 7;
    int ss0 = sl0 ^ (r0 & 7), ss1 = sl1 ^ (r1 & 7);
    const u16* kbase = qkv + 768 + h * 64;
    const u16* vtb = vt + (size_t)bh * 64 * S_LEN;
    const int od0 = w * 1024, od1 = w * 1024 + 4096;
    char* Pw = (char*)PsB[w];

    auto stageKV = [&](int c, int kb) {
        gload16(kbase + ((size_t)(kb * 64 + r0) * B_SZ + b) * QKV_N + ss0 * 8, (char*)KsB[c] + od0);
        gload16(kbase + ((size_t)(kb * 64 + r1) * B_SZ + b) * QKV_N + ss1 * 8, (char*)KsB[c] + od1);
        gload16(vtb + (size_t)r0 * S_LEN + kb * 64 + ss0 * 8, (char*)VtB[c] + od0);
        gload16(vtb + (size_t)r1 * S_LEN + kb * 64 + ss1 * 8, (char*)VtB[c] + od1);
    };

    stageKV(0, 0);

    for (int kb = 0; kb < S_LEN / 64; ++kb) {
        __syncthreads();
        if (kb + 1 < S_LEN / 64) stageKV((kb + 1) & 1, kb + 1);
        const char* Ks  = (const char*)KsB[kb & 1];
        const char* Vts = (const char*)VtB[kb & 1];

        // S'[key][q] = K . Q'^T  (already log2-scaled)
        f32x4 sacc[4] = {};
#pragma unroll
        for (int f = 0; f < 4; ++f) {
            int r = f * 16 + fr;
#pragma unroll
            for (int s = 0; s < 2; ++s) {
                int slot = (s * 4 + fg) ^ (r & 7);
                short8 kf = *(const short8*)(Ks + r * 128 + slot * 16);
                sacc[f] = __builtin_amdgcn_mfma_f32_16x16x32_bf16(kf, qf[s], sacc[f], 0, 0, 0);
            }
        }

        float p[16];
#pragma unroll
        for (int f = 0; f < 4; ++f)
#pragma unroll
            for (int r = 0; r < 4; ++r)
                p[f * 4 + r] = sacc[f][r];

        float mx = p[0];
#pragma unroll
        for (int i = 1; i < 16; ++i) mx = fmaxf(mx, p[i]);
        mx = fmaxf(mx, __shfl_xor(mx, 16));
        mx = fmaxf(mx, __shfl_xor(mx, 32));

        if (!__all(mx - m2 <= 8.f)) {      // defer-max: rescale only on growth
            float mnew = fmaxf(m2, mx);
            float alpha = fast_exp2(m2 - mnew);
            l_run *= alpha;
            m2 = mnew;
            float a0 = __shfl(alpha, fg4 + 0), a1 = __shfl(alpha, fg4 + 1);
            float a2 = __shfl(alpha, fg4 + 2), a3 = __shfl(alpha, fg4 + 3);
#pragma unroll
            for (int n = 0; n < 4; ++n) {
                O[n][0] *= a0; O[n][1] *= a1; O[n][2] *= a2; O[n][3] *= a3;
            }
        }

        float tsum = 0.f;
#pragma unroll
        for (int i = 0; i < 16; ++i) {
            p[i] = fast_exp2(p[i] - m2);
            tsum += p[i];
        }
        tsum += __shfl_xor(tsum, 16);
        tsum += __shfl_xor(tsum, 32);
        l_run += tsum;

        // P -> per-wave swizzled LDS via v_cvt_pk_bf16_f32
#pragma unroll
        for (int f = 0; f < 4; ++f) {
            u32 u0, u1;
            asm("v_cvt_pk_bf16_f32 %0, %1, %2" : "=v"(u0) : "v"(p[4 * f + 0]), "v"(p[4 * f + 1]));
            asm("v_cvt_pk_bf16_f32 %0, %1, %2" : "=v"(u1) : "v"(p[4 * f + 2]), "v"(p[4 * f + 3]));
            int slot = (f * 2 + (fg >> 1)) ^ (fr & 7);
            uint2 uu; uu.x = u0; uu.y = u1;
            *(uint2*)(Pw + fr * 128 + slot * 16 + (fg & 1) * 8) = uu;
        }
        asm volatile("s_waitcnt lgkmcnt(0)" ::: "memory");
        __builtin_amdgcn_sched_barrier(0);

        // O[q][dk] += P[q][key] * V[key][dk]
#pragma unroll
        for (int s = 0; s < 2; ++s) {
            int pslot = (s * 4 + fg) ^ (fr & 7);
            short8 pf = *(const short8*)(Pw + fr * 128 + pslot * 16);
#pragma unroll
            for (int n = 0; n < 4; ++n) {
                int vrow = n * 16 + fr;
                int vslot = (s * 4 + fg) ^ (vrow & 7);
                short8 vf = *(const short8*)(Vts + vrow * 128 + vslot * 16);
                O[n] = __builtin_amdgcn_mfma_f32_16x16x32_bf16(pf, vf, O[n], 0, 0, 0);
            }
        }
    }

    float li0 = __shfl(l_run, fg4 + 0), li1 = __shfl(l_run, fg4 + 1);
    float li2 = __shfl(l_run, fg4 + 2), li3 = __shfl(l_run, fg4 + 3);
    float i0 = 1.f / li0, i1 = 1.f / li1, i2 = 1.f / li2, i3 = 1.f / li3;
    int srow = qb * 64 + w * 16 + fg4;
    size_t tok0 = (size_t)srow * B_SZ + b;
#pragma unroll
    for (int n = 0; n < 4; ++n) {
        int col = h * 64 + n * 16 + fr;
        ctx[(tok0 + 0) * D_MODEL + col] = f2bf(O[n][0] * i0);
        ctx[(tok0 + 2) * D_MODEL + col] = f2bf(O[n][1] * i1);
        ctx[(tok0 + 4) * D_MODEL + col] = f2bf(O[n][2] * i2);
        ctx[(tok0 + 6) * D_MODEL + col] = f2bf(O[n][3] * i3);
    }
}

// ---------------------------------------------------------------------------
extern "C" void kernel_launch(void* const* d_in, const int* in_sizes, int n_in,
                              void* d_out, int out_size, void* d_ws, size_t ws_size,
                              hipStream_t stream)
{
    (void)in_sizes; (void)n_in; (void)out_size; (void)ws_size;
    const float* x   = (const float*)d_in[0];
    const float* wq  = (const float*)d_in[1];
    const float* bq  = (const float*)d_in[2];
    const float* wk  = (const float*)d_in[3];
    const float* bk  = (const float*)d_in[4];
    const float* wv  = (const float*)d_in[5];
    const float* bv  = (const float*)d_in[6];
    const float* wo  = (const float*)d_in[7];
    const float* bo  = (const float*)d_in[8];
    const float* g1  = (const float*)d_in[9];
    const float* b1  = (const float*)d_in[10];
    const float* g2  = (const float*)d_in[11];
    const float* b2  = (const float*)d_in[12];
    const float* w1  = (const float*)d_in[13];
    const float* bb1 = (const float*)d_in[14];
    const float* w2  = (const float*)d_in[15];
    const float* bb2 = (const float*)d_in[16];
    float* out = (float*)d_out;

    const size_t ND = (size_t)N_TOK * D_MODEL;
    char* p = (char*)d_ws;
    u16* z    = (u16*)p;                  // z1 / ctx / z2 ; FFN2 part0
    p += ND * 2;
    u16* qkv  = (u16*)p;                  // qkv ; WO partials ; hbuf start
    u16* hbuf = (u16*)p;
    p += (size_t)N_TOK * QKV_N * 2;
    u16* vtb  = (u16*)p;
    p += (size_t)B_SZ * N_HEADS * 64 * S_LEN * 2;
    u16* wqkvb = (u16*)p;                 // weights bf16 (contiguous) ; FFN2 part1
    p += (size_t)QKV_N * D_MODEL * 2;
    u16* wob   = (u16*)p; p += (size_t)D_MODEL * D_MODEL * 2;
    u16* w1b   = (u16*)p; p += (size_t)DFF * D_MODEL * 2;
    u16* w2b   = (u16*)p; p += (size_t)D_MODEL * DFF * 2;
    float* biasqkv = (float*)p;

    u16* wop0 = qkv;            // WO split-K partials (qkv dead after attn)
    u16* wop1 = qkv + ND;
    u16* fp0  = z;              // FFN2 partials (z, weight regions dead)
    u16* fp1  = wqkvb;

    dim3 blk(256);

    cvt_all<<<6912, blk, 0, stream>>>(wq, wk, wv, wo, w1, w2, wqkvb);
    concat_bias<<<9, blk, 0, stream>>>(bq, bk, bv, biasqkv);

    // z1 = LN(x)
    ln_kernel<<<N_TOK, blk, 0, stream>>>(x, g1, b1, z);
    // qkv = z1 @ Wqkv^T + b  (q scaled, v -> vtb transposed)
    gemm_mfma<1><<<dim3(QKV_N / 128, N_TOK / 128), blk, 0, stream>>>(
        z, wqkvb, biasqkv, qkv, vtb, QKV_N, D_MODEL, D_MODEL, D_MODEL, 0);
    // ctx = attention -> z
    attn_mfma<<<dim3(S_LEN / 64, B_SZ * N_HEADS), blk, 0, stream>>>(qkv, vtb, z);
    // WO split-K=2 partials
    gemm_mfma<4><<<dim3(D_MODEL / 128, N_TOK / 128, 2), blk, 0, stream>>>(
        z, wob, nullptr, wop0, wop1, D_MODEL, 384, D_MODEL, D_MODEL, 384);
    // x1 = x + p0 + p1 + bo (fp32 -> out); z2 = LN(x1) (bf16 -> z)
    ln_fuse<<<N_TOK, blk, 0, stream>>>(x, wop0, wop1, bo, g2, b2, out, z);
    // h = ELU(z2 @ w1^T + bb1)  (hbuf overwrites dead WO partials)
    gemm_mfma<3><<<dim3(DFF / 128, N_TOK / 128), blk, 0, stream>>>(
        z, w1b, bb1, hbuf, nullptr, DFF, D_MODEL, D_MODEL, D_MODEL, 0);
    // FFN2 split-K=2 partials
    gemm_mfma<4><<<dim3(D_MODEL / 128, N_TOK / 128, 2), blk, 0, stream>>>(
        hbuf, w2b, nullptr, fp0, fp1, D_MODEL, 1536, DFF, DFF, 1536);
    // out = out(x1) + fp0 + fp1 + bb2
    reduce_add<<<N_TOK * D_MODEL / 4 / 256, blk, 0, stream>>>(fp0, fp1, bb2, out, out);
}

// Round 6
// 202.649 us; speedup vs baseline: 8.3661x; 1.0251x over previous
//
#include <hip/hip_runtime.h>
#include <hip/hip_bf16.h>
#include <math.h>

#define S_LEN   2048
#define B_SZ    2
#define D_MODEL 768
#define N_HEADS 12
#define DFF     3072
#define N_TOK   4096
#define EPS     1e-5f
#define QKV_N   2304
#define SLOG2E  0.18033688011112042f   // 0.125 * log2(e)

typedef __attribute__((ext_vector_type(8))) short short8;
typedef __attribute__((ext_vector_type(4))) float f32x4;
typedef unsigned long long u64;
typedef unsigned short u16;
typedef unsigned u32;

__device__ __forceinline__ void gload16(const void* g, void* l) {
    __builtin_amdgcn_global_load_lds(
        (const __attribute__((address_space(1))) void*)g,
        (__attribute__((address_space(3))) void*)l, 16, 0, 0);
}
__device__ __forceinline__ u16 f2bf(float x) {
    union { float f; unsigned u; } c; c.f = x;
    unsigned r = c.u + 0x7FFF + ((c.u >> 16) & 1);
    return (u16)(r >> 16);
}
__device__ __forceinline__ float bf2f(u16 u) {
    union { unsigned u; float f; } c; c.u = ((unsigned)u) << 16; return c.f;
}
__device__ __forceinline__ float fast_exp2(float x) {
    float r; asm("v_exp_f32 %0, %1" : "=v"(r) : "v"(x)); return r;
}

// ---------------------------------------------------------------------------
// All six weight matrices -> bf16 in one launch (dsts contiguous)
// order: wq | wk | wv | wo | w1 | w2   (float4 granularity)
// ---------------------------------------------------------------------------
__global__ __launch_bounds__(256) void cvt_all(
    const float* __restrict__ wq, const float* __restrict__ wk,
    const float* __restrict__ wv, const float* __restrict__ wo,
    const float* __restrict__ w1, const float* __restrict__ w2,
    u16* __restrict__ dst)
{
    const int W = 147456;  // 768*768/4
    int i = blockIdx.x * 256 + threadIdx.x;
    const float* src; int off;
    if      (i <     W) { src = wq; off = 0;     }
    else if (i < 2 * W) { src = wk; off = W;     }
    else if (i < 3 * W) { src = wv; off = 2 * W; }
    else if (i < 4 * W) { src = wo; off = 3 * W; }
    else if (i < 8 * W) { src = w1; off = 4 * W; }
    else                { src = w2; off = 8 * W; }
    float4 v = ((const float4*)src)[i - off];
    union { u16 u[4]; u64 ll; } o;
    o.u[0] = f2bf(v.x); o.u[1] = f2bf(v.y); o.u[2] = f2bf(v.z); o.u[3] = f2bf(v.w);
    ((u64*)dst)[i] = o.ll;
}

__global__ __launch_bounds__(256) void concat_bias(
    const float* __restrict__ bq, const float* __restrict__ bk,
    const float* __restrict__ bv, float* __restrict__ d)
{
    int i = blockIdx.x * 256 + threadIdx.x;
    if (i < 768) d[i] = bq[i];
    else if (i < 1536) d[i] = bk[i - 768];
    else d[i] = bv[i - 1536];
}

// ---------------------------------------------------------------------------
__global__ __launch_bounds__(256) void ln_kernel(
    const float* __restrict__ x, const float* __restrict__ g,
    const float* __restrict__ b, u16* __restrict__ z)
{
    int row = blockIdx.x;
    const float* xr = x + (size_t)row * D_MODEL;
    u16* zr = z + (size_t)row * D_MODEL;
    int t = threadIdx.x;
    float loc[3];
    float s1 = 0.f, s2 = 0.f;
#pragma unroll
    for (int i = 0; i < 3; ++i) {
        float v = xr[t + 256 * i];
        loc[i] = v; s1 += v; s2 += v * v;
    }
#pragma unroll
    for (int off = 32; off > 0; off >>= 1) {
        s1 += __shfl_down(s1, off);
        s2 += __shfl_down(s2, off);
    }
    __shared__ float r1[4], r2[4];
    __shared__ float mu_s, is_s;
    int wave = t >> 6, lane = t & 63;
    if (lane == 0) { r1[wave] = s1; r2[wave] = s2; }
    __syncthreads();
    if (t == 0) {
        float a = r1[0] + r1[1] + r1[2] + r1[3];
        float c = r2[0] + r2[1] + r2[2] + r2[3];
        float mu = a * (1.f / D_MODEL);
        float var = c * (1.f / D_MODEL) - mu * mu;
        mu_s = mu; is_s = rsqrtf(var + EPS);
    }
    __syncthreads();
    float mu = mu_s, istd = is_s;
#pragma unroll
    for (int i = 0; i < 3; ++i) {
        int c = t + 256 * i;
        zr[c] = f2bf((loc[i] - mu) * istd * g[c] + b[c]);
    }
}

// ---------------------------------------------------------------------------
// x1 = x + bf(p0) + bf(p1) + bres ; xout fp32 x1 ; z = bf16 LN(x1, g, b)
// ---------------------------------------------------------------------------
__global__ __launch_bounds__(256) void ln_fuse(
    const float* __restrict__ x, const u16* __restrict__ p0,
    const u16* __restrict__ p1, const float* __restrict__ bres,
    const float* __restrict__ g, const float* __restrict__ b,
    float* __restrict__ xout, u16* __restrict__ z)
{
    int row = blockIdx.x;
    const float* xr = x + (size_t)row * D_MODEL;
    const u16* p0r = p0 + (size_t)row * D_MODEL;
    const u16* p1r = p1 + (size_t)row * D_MODEL;
    int t = threadIdx.x;
    float loc[3];
    float s1 = 0.f, s2 = 0.f;
#pragma unroll
    for (int i = 0; i < 3; ++i) {
        int c = t + 256 * i;
        float v = xr[c] + bf2f(p0r[c]) + bf2f(p1r[c]) + bres[c];
        loc[i] = v; s1 += v; s2 += v * v;
    }
#pragma unroll
    for (int off = 32; off > 0; off >>= 1) {
        s1 += __shfl_down(s1, off);
        s2 += __shfl_down(s2, off);
    }
    __shared__ float r1[4], r2[4];
    __shared__ float mu_s, is_s;
    int wave = t >> 6, lane = t & 63;
    if (lane == 0) { r1[wave] = s1; r2[wave] = s2; }
    __syncthreads();
    if (t == 0) {
        float a = r1[0] + r1[1] + r1[2] + r1[3];
        float c = r2[0] + r2[1] + r2[2] + r2[3];
        float mu = a * (1.f / D_MODEL);
        float var = c * (1.f / D_MODEL) - mu * mu;
        mu_s = mu; is_s = rsqrtf(var + EPS);
    }
    __syncthreads();
    float mu = mu_s, istd = is_s;
    float* xo = xout + (size_t)row * D_MODEL;
    u16* zr = z + (size_t)row * D_MODEL;
#pragma unroll
    for (int i = 0; i < 3; ++i) {
        int c = t + 256 * i;
        xo[c] = loc[i];
        zr[c] = f2bf((loc[i] - mu) * istd * g[c] + b[c]);
    }
}

// ---------------------------------------------------------------------------
// bf16 MFMA GEMM, 128x128 tile, BK=32, 3-buffer 2-deep pipeline (counted vmcnt).
// MODE 1: QKV (q scaled by SLOG2E; q,k -> qkv; v -> transposed vt)
// MODE 3: bf16 out + ELU | MODE 4: split-K bf16 partial (z picks outp/vt)
// ---------------------------------------------------------------------------
template <int MODE>
__global__ __launch_bounds__(256) void gemm_mfma(
    const u16* __restrict__ A, const u16* __restrict__ W,
    const float* __restrict__ bias, void* __restrict__ outp,
    u16* __restrict__ vt, int Ncols, int K, int lda, int ldw, int koff)
{
    __shared__ short AsB[3][128 * 32];
    __shared__ short BsB[3][128 * 32];

    const int t = threadIdx.x;
    const int lane = t & 63, w = t >> 6;
    const int wr = w >> 1, wc = w & 1;
    const int row0 = blockIdx.y * 128, col0 = blockIdx.x * 128;
    const int fr = lane & 15, fg = lane >> 4;

    if (MODE == 4) {
        A += (size_t)blockIdx.z * koff;
        W += (size_t)blockIdx.z * koff;
    }

    int o0 = w * 1024 + lane * 16;
    int r0s = o0 >> 6,          sl0 = (o0 >> 4) & 3;
    int r1s = (o0 + 4096) >> 6, sl1 = ((o0 + 4096) >> 4) & 3;
    int ss0 = sl0 ^ ((r0s >> 1) & 3);
    int ss1 = sl1 ^ ((r1s >> 1) & 3);
    const u16* Asrc0 = A + (size_t)(row0 + r0s) * lda + ss0 * 8;
    const u16* Asrc1 = A + (size_t)(row0 + r1s) * lda + ss1 * 8;
    const u16* Bsrc0 = W + (size_t)(col0 + r0s) * ldw + ss0 * 8;
    const u16* Bsrc1 = W + (size_t)(col0 + r1s) * ldw + ss1 * 8;
    const int od0 = w * 1024, od1 = w * 1024 + 4096;

    f32x4 acc[4][4] = {};
    const int nt = K / 32;

    auto stage = [&](int c, int k0) {
        gload16(Asrc0 + k0, (char*)AsB[c] + od0);
        gload16(Asrc1 + k0, (char*)AsB[c] + od1);
        gload16(Bsrc0 + k0, (char*)BsB[c] + od0);
        gload16(Bsrc1 + k0, (char*)BsB[c] + od1);
    };

    stage(0, 0);
    stage(1, 32);

    for (int tt = 0; tt < nt; ++tt) {
        if (tt + 1 < nt)
            asm volatile("s_waitcnt vmcnt(4)\n\ts_barrier" ::: "memory");
        else
            asm volatile("s_waitcnt vmcnt(0)\n\ts_barrier" ::: "memory");
        if (tt + 2 < nt) stage((tt + 2) % 3, (tt + 2) * 32);

        const char* As = (const char*)AsB[tt % 3];
        const char* Bs = (const char*)BsB[tt % 3];
        short8 af[4], bfr[4];
#pragma unroll
        for (int m = 0; m < 4; ++m) {
            int r = wr * 64 + m * 16 + fr;
            af[m] = *(const short8*)(As + r * 64 + ((fg ^ ((r >> 1) & 3)) << 4));
        }
#pragma unroll
        for (int n = 0; n < 4; ++n) {
            int r = wc * 64 + n * 16 + fr;
            bfr[n] = *(const short8*)(Bs + r * 64 + ((fg ^ ((r >> 1) & 3)) << 4));
        }
#pragma unroll
        for (int m = 0; m < 4; ++m)
#pragma unroll
            for (int n = 0; n < 4; ++n)
                acc[m][n] = __builtin_amdgcn_mfma_f32_16x16x32_bf16(
                    af[m], bfr[n], acc[m][n], 0, 0, 0);
    }

    u16* pout16 = nullptr;
    if (MODE == 4) pout16 = blockIdx.z ? vt : (u16*)outp;

#pragma unroll
    for (int m = 0; m < 4; ++m) {
        int rbase = row0 + wr * 64 + m * 16 + fg * 4;
#pragma unroll
        for (int n = 0; n < 4; ++n) {
            int col = col0 + wc * 64 + n * 16 + fr;
            float bv = (MODE == 4) ? 0.f : bias[col];
            if (MODE == 1 && col >= 1536) {
                int cc = col - 1536, hh = cc >> 6, dk = cc & 63;
                int s_a = rbase >> 1;
                float v0 = acc[m][n][0] + bv, v1 = acc[m][n][1] + bv;
                float v2 = acc[m][n][2] + bv, v3 = acc[m][n][3] + bv;
                unsigned lo = (unsigned)f2bf(v0) | ((unsigned)f2bf(v2) << 16);
                unsigned hi = (unsigned)f2bf(v1) | ((unsigned)f2bf(v3) << 16);
                *(unsigned*)&vt[((size_t)hh * 64 + dk) * 2048 + s_a] = lo;
                *(unsigned*)&vt[((size_t)(N_HEADS + hh) * 64 + dk) * 2048 + s_a] = hi;
            } else {
#pragma unroll
                for (int r = 0; r < 4; ++r) {
                    int row = rbase + r;
                    float v = acc[m][n][r] + bv;
                    if (MODE == 3) {
                        v = v > 0.f ? v : expm1f(v);
                        ((u16*)outp)[(size_t)row * Ncols + col] = f2bf(v);
                    } else if (MODE == 4) {
                        pout16[(size_t)row * 768 + col] = f2bf(v);
                    } else {  // MODE 1, q/k
                        if (col < 768) v *= SLOG2E;   // fold softmax scale+log2e into Q
                        ((u16*)outp)[(size_t)row * QKV_N + col] = f2bf(v);
                    }
                }
            }
        }
    }
}

// ---------------------------------------------------------------------------
// out = res + bf(p0) + bf(p1) + bias   (res may alias out)
// ---------------------------------------------------------------------------
__global__ __launch_bounds__(256) void reduce_add(
    const u16* __restrict__ p0, const u16* __restrict__ p1,
    const float* __restrict__ bias, const float* __restrict__ res,
    float* __restrict__ out)
{
    int i = blockIdx.x * 256 + threadIdx.x;
    int col4 = i % (D_MODEL / 4);
    u64 a = ((const u64*)p0)[i];
    u64 c = ((const u64*)p1)[i];
    float4 o = ((const float4*)res)[i];
    float4 bb = ((const float4*)bias)[col4];
    o.x += bf2f((u16)a)         + bf2f((u16)c)         + bb.x;
    o.y += bf2f((u16)(a >> 16)) + bf2f((u16)(c >> 16)) + bb.y;
    o.z += bf2f((u16)(a >> 32)) + bf2f((u16)(c >> 32)) + bb.z;
    o.w += bf2f((u16)(a >> 48)) + bf2f((u16)(c >> 48)) + bb.w;
    ((float4*)out)[i] = o;
}

// ---------------------------------------------------------------------------
// Flash attention, bf16 MFMA, K/V double-buffered (round-4 proven structure).
// Scores arrive in exp2 domain (Q pre-scaled by SLOG2E). Defer-max THR=8.
// NEW vs r4: l-sum via MFMA ones-trick (l_acc[r] = l for q=fg*4+r, no serial
// sum chain, no end shuffles); s_setprio around MFMA clusters.
// ---------------------------------------------------------------------------
__global__ __launch_bounds__(256) void attn_mfma(
    const u16* __restrict__ qkv, const u16* __restrict__ vt,
    u16* __restrict__ ctx)
{
    __shared__ short KsB[2][64 * 64];
    __shared__ short VtB[2][64 * 64];
    __shared__ short PsB[4][16 * 64];

    const int t = threadIdx.x, lane = t & 63, w = t >> 6;
    const int fr = lane & 15, fg = lane >> 4;
    const int fg4 = fg * 4;
    const int qb = blockIdx.x, bh = blockIdx.y;
    const int b = bh / N_HEADS, h = bh % N_HEADS;

    short8 qf[2];
    {
        int srow = qb * 64 + w * 16 + fr;
        size_t tok = (size_t)srow * B_SZ + b;
#pragma unroll
        for (int s = 0; s < 2; ++s)
            qf[s] = *(const short8*)(qkv + tok * QKV_N + h * 64 + s * 32 + fg * 8);
    }

    const short8 ones8 = { (short)0x3F80, (short)0x3F80, (short)0x3F80, (short)0x3F80,
                           (short)0x3F80, (short)0x3F80, (short)0x3F80, (short)0x3F80 };

    float m2 = -1e30f;
    f32x4 l_acc = {};
    f32x4 O[4] = {};

    int o0 = w * 1024 + lane * 16;
    int r0 = o0 >> 7,          sl0 = (o0 >> 4) & 7;
    int r1 = (o0 + 4096) >> 7, sl1 = ((o0 + 4096) >> 4) & 7;
    int ss0 = sl0 ^ (r0 & 7), ss1 = sl1 ^ (r1 & 7);
    const u16* kbase = qkv + 768 + h * 64;
    const u16* vtb = vt + (size_t)bh * 64 * S_LEN;
    const int od0 = w * 1024, od1 = w * 1024 + 4096;
    char* Pw = (char*)PsB[w];

    auto stageKV = [&](int c, int kb) {
        gload16(kbase + ((size_t)(kb * 64 + r0) * B_SZ + b) * QKV_N + ss0 * 8, (char*)KsB[c] + od0);
        gload16(kbase + ((size_t)(kb * 64 + r1) * B_SZ + b) * QKV_N + ss1 * 8, (char*)KsB[c] + od1);
        gload16(vtb + (size_t)r0 * S_LEN + kb * 64 + ss0 * 8, (char*)VtB[c] + od0);
        gload16(vtb + (size_t)r1 * S_LEN + kb * 64 + ss1 * 8, (char*)VtB[c] + od1);
    };

    stageKV(0, 0);

    for (int kb = 0; kb < S_LEN / 64; ++kb) {
        __syncthreads();
        if (kb + 1 < S_LEN / 64) stageKV((kb + 1) & 1, kb + 1);
        const char* Ks  = (const char*)KsB[kb & 1];
        const char* Vts = (const char*)VtB[kb & 1];

        // S'[key][q] = K . Q'^T  (already log2-scaled)
        f32x4 sacc[4] = {};
        __builtin_amdgcn_s_setprio(1);
#pragma unroll
        for (int f = 0; f < 4; ++f) {
            int r = f * 16 + fr;
#pragma unroll
            for (int s = 0; s < 2; ++s) {
                int slot = (s * 4 + fg) ^ (r & 7);
                short8 kf = *(const short8*)(Ks + r * 128 + slot * 16);
                sacc[f] = __builtin_amdgcn_mfma_f32_16x16x32_bf16(kf, qf[s], sacc[f], 0, 0, 0);
            }
        }
        __builtin_amdgcn_s_setprio(0);

        float p[16];
        float mx = -1e30f;
#pragma unroll
        for (int f = 0; f < 4; ++f)
#pragma unroll
            for (int r = 0; r < 4; ++r) {
                float vv = sacc[f][r];
                p[f * 4 + r] = vv;
                mx = fmaxf(mx, vv);
            }
        mx = fmaxf(mx, __shfl_xor(mx, 16));
        mx = fmaxf(mx, __shfl_xor(mx, 32));

        if (!__all(mx - m2 <= 8.f)) {      // defer-max: rescale only on growth
            float mnew = fmaxf(m2, mx);
            float alpha = fast_exp2(m2 - mnew);
            m2 = mnew;
            float a0 = __shfl(alpha, fg4 + 0), a1 = __shfl(alpha, fg4 + 1);
            float a2 = __shfl(alpha, fg4 + 2), a3 = __shfl(alpha, fg4 + 3);
#pragma unroll
            for (int n = 0; n < 4; ++n) {
                O[n][0] *= a0; O[n][1] *= a1; O[n][2] *= a2; O[n][3] *= a3;
            }
            l_acc[0] *= a0; l_acc[1] *= a1; l_acc[2] *= a2; l_acc[3] *= a3;
        }

#pragma unroll
        for (int i = 0; i < 16; ++i)
            p[i] = fast_exp2(p[i] - m2);

        // P -> per-wave swizzled LDS via v_cvt_pk_bf16_f32
#pragma unroll
        for (int f = 0; f < 4; ++f) {
            u32 u0, u1;
            asm("v_cvt_pk_bf16_f32 %0, %1, %2" : "=v"(u0) : "v"(p[4 * f + 0]), "v"(p[4 * f + 1]));
            asm("v_cvt_pk_bf16_f32 %0, %1, %2" : "=v"(u1) : "v"(p[4 * f + 2]), "v"(p[4 * f + 3]));
            int slot = (f * 2 + (fg >> 1)) ^ (fr & 7);
            uint2 uu; uu.x = u0; uu.y = u1;
            *(uint2*)(Pw + fr * 128 + slot * 16 + (fg & 1) * 8) = uu;
        }
        asm volatile("s_waitcnt lgkmcnt(0)" ::: "memory");
        __builtin_amdgcn_sched_barrier(0);

        // O[q][dk] += P[q][key] * V[key][dk];  l_acc += P row-sums (ones trick)
        __builtin_amdgcn_s_setprio(1);
#pragma unroll
        for (int s = 0; s < 2; ++s) {
            int pslot = (s * 4 + fg) ^ (fr & 7);
            short8 pf = *(const short8*)(Pw + fr * 128 + pslot * 16);
            l_acc = __builtin_amdgcn_mfma_f32_16x16x32_bf16(pf, ones8, l_acc, 0, 0, 0);
#pragma unroll
            for (int n = 0; n < 4; ++n) {
                int vrow = n * 16 + fr;
                int vslot = (s * 4 + fg) ^ (vrow & 7);
                short8 vf = *(const short8*)(Vts + vrow * 128 + vslot * 16);
                O[n] = __builtin_amdgcn_mfma_f32_16x16x32_bf16(pf, vf, O[n], 0, 0, 0);
            }
        }
        __builtin_amdgcn_s_setprio(0);
    }

    // l_acc[r] = l for q-row fg4+r (replicated across fr) -> direct normalize
    float i0 = 1.f / l_acc[0], i1 = 1.f / l_acc[1];
    float i2 = 1.f / l_acc[2], i3 = 1.f / l_acc[3];
    int srow = qb * 64 + w * 16 + fg4;
    size_t tok0 = (size_t)srow * B_SZ + b;
#pragma unroll
    for (int n = 0; n < 4; ++n) {
        int col = h * 64 + n * 16 + fr;
        ctx[(tok0 + 0) * D_MODEL + col] = f2bf(O[n][0] * i0);
        ctx[(tok0 + 2) * D_MODEL + col] = f2bf(O[n][1] * i1);
        ctx[(tok0 + 4) * D_MODEL + col] = f2bf(O[n][2] * i2);
        ctx[(tok0 + 6) * D_MODEL + col] = f2bf(O[n][3] * i3);
    }
}

// ---------------------------------------------------------------------------
extern "C" void kernel_launch(void* const* d_in, const int* in_sizes, int n_in,
                              void* d_out, int out_size, void* d_ws, size_t ws_size,
                              hipStream_t stream)
{
    (void)in_sizes; (void)n_in; (void)out_size; (void)ws_size;
    const float* x   = (const float*)d_in[0];
    const float* wq  = (const float*)d_in[1];
    const float* bq  = (const float*)d_in[2];
    const float* wk  = (const float*)d_in[3];
    const float* bk  = (const float*)d_in[4];
    const float* wv  = (const float*)d_in[5];
    const float* bv  = (const float*)d_in[6];
    const float* wo  = (const float*)d_in[7];
    const float* bo  = (const float*)d_in[8];
    const float* g1  = (const float*)d_in[9];
    const float* b1  = (const float*)d_in[10];
    const float* g2  = (const float*)d_in[11];
    const float* b2  = (const float*)d_in[12];
    const float* w1  = (const float*)d_in[13];
    const float* bb1 = (const float*)d_in[14];
    const float* w2  = (const float*)d_in[15];
    const float* bb2 = (const float*)d_in[16];
    float* out = (float*)d_out;

    const size_t ND = (size_t)N_TOK * D_MODEL;
    char* p = (char*)d_ws;
    u16* z    = (u16*)p;                  // z1 / ctx / z2 ; FFN2 part0
    p += ND * 2;
    u16* qkv  = (u16*)p;                  // qkv ; WO partials ; hbuf start
    u16* hbuf = (u16*)p;
    p += (size_t)N_TOK * QKV_N * 2;
    u16* vtb  = (u16*)p;
    p += (size_t)B_SZ * N_HEADS * 64 * S_LEN * 2;
    u16* wqkvb = (u16*)p;                 // weights bf16 (contiguous) ; FFN2 part1
    p += (size_t)QKV_N * D_MODEL * 2;
    u16* wob   = (u16*)p; p += (size_t)D_MODEL * D_MODEL * 2;
    u16* w1b   = (u16*)p; p += (size_t)DFF * D_MODEL * 2;
    u16* w2b   = (u16*)p; p += (size_t)D_MODEL * DFF * 2;
    float* biasqkv = (float*)p;

    u16* wop0 = qkv;            // WO split-K partials (qkv dead after attn)
    u16* wop1 = qkv + ND;
    u16* fp0  = z;              // FFN2 partials (z, weight regions dead)
    u16* fp1  = wqkvb;

    dim3 blk(256);

    cvt_all<<<6912, blk, 0, stream>>>(wq, wk, wv, wo, w1, w2, wqkvb);
    concat_bias<<<9, blk, 0, stream>>>(bq, bk, bv, biasqkv);

    // z1 = LN(x)
    ln_kernel<<<N_TOK, blk, 0, stream>>>(x, g1, b1, z);
    // qkv = z1 @ Wqkv^T + b  (q scaled, v -> vtb transposed)
    gemm_mfma<1><<<dim3(QKV_N / 128, N_TOK / 128), blk, 0, stream>>>(
        z, wqkvb, biasqkv, qkv, vtb, QKV_N, D_MODEL, D_MODEL, D_MODEL, 0);
    // ctx = attention -> z
    attn_mfma<<<dim3(S_LEN / 64, B_SZ * N_HEADS), blk, 0, stream>>>(qkv, vtb, z);
    // WO split-K=2 partials
    gemm_mfma<4><<<dim3(D_MODEL / 128, N_TOK / 128, 2), blk, 0, stream>>>(
        z, wob, nullptr, wop0, wop1, D_MODEL, 384, D_MODEL, D_MODEL, 384);
    // x1 = x + p0 + p1 + bo (fp32 -> out); z2 = LN(x1) (bf16 -> z)
    ln_fuse<<<N_TOK, blk, 0, stream>>>(x, wop0, wop1, bo, g2, b2, out, z);
    // h = ELU(z2 @ w1^T + bb1)  (hbuf overwrites dead WO partials)
    gemm_mfma<3><<<dim3(DFF / 128, N_TOK / 128), blk, 0, stream>>>(
        z, w1b, bb1, hbuf, nullptr, DFF, D_MODEL, D_MODEL, D_MODEL, 0);
    // FFN2 split-K=2 partials
    gemm_mfma<4><<<dim3(D_MODEL / 128, N_TOK / 128, 2), blk, 0, stream>>>(
        hbuf, w2b, nullptr, fp0, fp1, D_MODEL, 1536, DFF, DFF, 1536);
    // out = out(x1) + fp0 + fp1 + bb2
    reduce_add<<<(int)(ND / 4 / 256), blk, 0, stream>>>(fp0, fp1, bb2, out, out);
}

// Round 7
// 202.495 us; speedup vs baseline: 8.3725x; 1.0008x over previous
//
#include <hip/hip_runtime.h>
#include <hip/hip_bf16.h>
#include <math.h>

#define S_LEN   2048
#define B_SZ    2
#define D_MODEL 768
#define N_HEADS 12
#define DFF     3072
#define N_TOK   4096
#define EPS     1e-5f
#define QKV_N   2304
#define SLOG2E  0.18033688011112042f   // 0.125 * log2(e)
#define NSPLIT  2
#define NTILE   (S_LEN / 64 / NSPLIT)  // 16 KV-tiles per split

typedef __attribute__((ext_vector_type(8))) short short8;
typedef __attribute__((ext_vector_type(4))) float f32x4;
typedef unsigned long long u64;
typedef unsigned short u16;
typedef unsigned u32;

__device__ __forceinline__ void gload16(const void* g, void* l) {
    __builtin_amdgcn_global_load_lds(
        (const __attribute__((address_space(1))) void*)g,
        (__attribute__((address_space(3))) void*)l, 16, 0, 0);
}
__device__ __forceinline__ u16 f2bf(float x) {
    union { float f; unsigned u; } c; c.f = x;
    unsigned r = c.u + 0x7FFF + ((c.u >> 16) & 1);
    return (u16)(r >> 16);
}
__device__ __forceinline__ float bf2f(u16 u) {
    union { unsigned u; float f; } c; c.u = ((unsigned)u) << 16; return c.f;
}
__device__ __forceinline__ float fast_exp2(float x) {
    float r; asm("v_exp_f32 %0, %1" : "=v"(r) : "v"(x)); return r;
}

// ---------------------------------------------------------------------------
// All six weight matrices -> bf16 in one launch (dsts contiguous)
// ---------------------------------------------------------------------------
__global__ __launch_bounds__(256) void cvt_all(
    const float* __restrict__ wq, const float* __restrict__ wk,
    const float* __restrict__ wv, const float* __restrict__ wo,
    const float* __restrict__ w1, const float* __restrict__ w2,
    u16* __restrict__ dst)
{
    const int W = 147456;  // 768*768/4
    int i = blockIdx.x * 256 + threadIdx.x;
    const float* src; int off;
    if      (i <     W) { src = wq; off = 0;     }
    else if (i < 2 * W) { src = wk; off = W;     }
    else if (i < 3 * W) { src = wv; off = 2 * W; }
    else if (i < 4 * W) { src = wo; off = 3 * W; }
    else if (i < 8 * W) { src = w1; off = 4 * W; }
    else                { src = w2; off = 8 * W; }
    float4 v = ((const float4*)src)[i - off];
    union { u16 u[4]; u64 ll; } o;
    o.u[0] = f2bf(v.x); o.u[1] = f2bf(v.y); o.u[2] = f2bf(v.z); o.u[3] = f2bf(v.w);
    ((u64*)dst)[i] = o.ll;
}

__global__ __launch_bounds__(256) void concat_bias(
    const float* __restrict__ bq, const float* __restrict__ bk,
    const float* __restrict__ bv, float* __restrict__ d)
{
    int i = blockIdx.x * 256 + threadIdx.x;
    if (i < 768) d[i] = bq[i];
    else if (i < 1536) d[i] = bk[i - 768];
    else d[i] = bv[i - 1536];
}

// ---------------------------------------------------------------------------
__global__ __launch_bounds__(256) void ln_kernel(
    const float* __restrict__ x, const float* __restrict__ g,
    const float* __restrict__ b, u16* __restrict__ z)
{
    int row = blockIdx.x;
    const float* xr = x + (size_t)row * D_MODEL;
    u16* zr = z + (size_t)row * D_MODEL;
    int t = threadIdx.x;
    float loc[3];
    float s1 = 0.f, s2 = 0.f;
#pragma unroll
    for (int i = 0; i < 3; ++i) {
        float v = xr[t + 256 * i];
        loc[i] = v; s1 += v; s2 += v * v;
    }
#pragma unroll
    for (int off = 32; off > 0; off >>= 1) {
        s1 += __shfl_down(s1, off);
        s2 += __shfl_down(s2, off);
    }
    __shared__ float r1[4], r2[4];
    __shared__ float mu_s, is_s;
    int wave = t >> 6, lane = t & 63;
    if (lane == 0) { r1[wave] = s1; r2[wave] = s2; }
    __syncthreads();
    if (t == 0) {
        float a = r1[0] + r1[1] + r1[2] + r1[3];
        float c = r2[0] + r2[1] + r2[2] + r2[3];
        float mu = a * (1.f / D_MODEL);
        float var = c * (1.f / D_MODEL) - mu * mu;
        mu_s = mu; is_s = rsqrtf(var + EPS);
    }
    __syncthreads();
    float mu = mu_s, istd = is_s;
#pragma unroll
    for (int i = 0; i < 3; ++i) {
        int c = t + 256 * i;
        zr[c] = f2bf((loc[i] - mu) * istd * g[c] + b[c]);
    }
}

// ---------------------------------------------------------------------------
// x1 = x + bf(p0) + bf(p1) + bres ; xout fp32 x1 ; z = bf16 LN(x1, g, b)
// ---------------------------------------------------------------------------
__global__ __launch_bounds__(256) void ln_fuse(
    const float* __restrict__ x, const u16* __restrict__ p0,
    const u16* __restrict__ p1, const float* __restrict__ bres,
    const float* __restrict__ g, const float* __restrict__ b,
    float* __restrict__ xout, u16* __restrict__ z)
{
    int row = blockIdx.x;
    const float* xr = x + (size_t)row * D_MODEL;
    const u16* p0r = p0 + (size_t)row * D_MODEL;
    const u16* p1r = p1 + (size_t)row * D_MODEL;
    int t = threadIdx.x;
    float loc[3];
    float s1 = 0.f, s2 = 0.f;
#pragma unroll
    for (int i = 0; i < 3; ++i) {
        int c = t + 256 * i;
        float v = xr[c] + bf2f(p0r[c]) + bf2f(p1r[c]) + bres[c];
        loc[i] = v; s1 += v; s2 += v * v;
    }
#pragma unroll
    for (int off = 32; off > 0; off >>= 1) {
        s1 += __shfl_down(s1, off);
        s2 += __shfl_down(s2, off);
    }
    __shared__ float r1[4], r2[4];
    __shared__ float mu_s, is_s;
    int wave = t >> 6, lane = t & 63;
    if (lane == 0) { r1[wave] = s1; r2[wave] = s2; }
    __syncthreads();
    if (t == 0) {
        float a = r1[0] + r1[1] + r1[2] + r1[3];
        float c = r2[0] + r2[1] + r2[2] + r2[3];
        float mu = a * (1.f / D_MODEL);
        float var = c * (1.f / D_MODEL) - mu * mu;
        mu_s = mu; is_s = rsqrtf(var + EPS);
    }
    __syncthreads();
    float mu = mu_s, istd = is_s;
    float* xo = xout + (size_t)row * D_MODEL;
    u16* zr = z + (size_t)row * D_MODEL;
#pragma unroll
    for (int i = 0; i < 3; ++i) {
        int c = t + 256 * i;
        xo[c] = loc[i];
        zr[c] = f2bf((loc[i] - mu) * istd * g[c] + b[c]);
    }
}

// ---------------------------------------------------------------------------
// bf16 MFMA GEMM, 128x128 tile, BK=32, 3-buffer 2-deep pipeline (counted vmcnt).
// MODE 1: QKV (q scaled by SLOG2E; q,k -> qkv; v -> transposed vt)
// MODE 3: bf16 out + ELU | MODE 4: split-K bf16 partial (z picks outp/vt)
// ---------------------------------------------------------------------------
template <int MODE>
__global__ __launch_bounds__(256) void gemm_mfma(
    const u16* __restrict__ A, const u16* __restrict__ W,
    const float* __restrict__ bias, void* __restrict__ outp,
    u16* __restrict__ vt, int Ncols, int K, int lda, int ldw, int koff)
{
    __shared__ short AsB[3][128 * 32];
    __shared__ short BsB[3][128 * 32];

    const int t = threadIdx.x;
    const int lane = t & 63, w = t >> 6;
    const int wr = w >> 1, wc = w & 1;
    const int row0 = blockIdx.y * 128, col0 = blockIdx.x * 128;
    const int fr = lane & 15, fg = lane >> 4;

    if (MODE == 4) {
        A += (size_t)blockIdx.z * koff;
        W += (size_t)blockIdx.z * koff;
    }

    int o0 = w * 1024 + lane * 16;
    int r0s = o0 >> 6,          sl0 = (o0 >> 4) & 3;
    int r1s = (o0 + 4096) >> 6, sl1 = ((o0 + 4096) >> 4) & 3;
    int ss0 = sl0 ^ ((r0s >> 1) & 3);
    int ss1 = sl1 ^ ((r1s >> 1) & 3);
    const u16* Asrc0 = A + (size_t)(row0 + r0s) * lda + ss0 * 8;
    const u16* Asrc1 = A + (size_t)(row0 + r1s) * lda + ss1 * 8;
    const u16* Bsrc0 = W + (size_t)(col0 + r0s) * ldw + ss0 * 8;
    const u16* Bsrc1 = W + (size_t)(col0 + r1s) * ldw + ss1 * 8;
    const int od0 = w * 1024, od1 = w * 1024 + 4096;

    f32x4 acc[4][4] = {};
    const int nt = K / 32;

    auto stage = [&](int c, int k0) {
        gload16(Asrc0 + k0, (char*)AsB[c] + od0);
        gload16(Asrc1 + k0, (char*)AsB[c] + od1);
        gload16(Bsrc0 + k0, (char*)BsB[c] + od0);
        gload16(Bsrc1 + k0, (char*)BsB[c] + od1);
    };

    stage(0, 0);
    stage(1, 32);

    for (int tt = 0; tt < nt; ++tt) {
        if (tt + 1 < nt)
            asm volatile("s_waitcnt vmcnt(4)\n\ts_barrier" ::: "memory");
        else
            asm volatile("s_waitcnt vmcnt(0)\n\ts_barrier" ::: "memory");
        if (tt + 2 < nt) stage((tt + 2) % 3, (tt + 2) * 32);

        const char* As = (const char*)AsB[tt % 3];
        const char* Bs = (const char*)BsB[tt % 3];
        short8 af[4], bfr[4];
#pragma unroll
        for (int m = 0; m < 4; ++m) {
            int r = wr * 64 + m * 16 + fr;
            af[m] = *(const short8*)(As + r * 64 + ((fg ^ ((r >> 1) & 3)) << 4));
        }
#pragma unroll
        for (int n = 0; n < 4; ++n) {
            int r = wc * 64 + n * 16 + fr;
            bfr[n] = *(const short8*)(Bs + r * 64 + ((fg ^ ((r >> 1) & 3)) << 4));
        }
#pragma unroll
        for (int m = 0; m < 4; ++m)
#pragma unroll
            for (int n = 0; n < 4; ++n)
                acc[m][n] = __builtin_amdgcn_mfma_f32_16x16x32_bf16(
                    af[m], bfr[n], acc[m][n], 0, 0, 0);
    }

    u16* pout16 = nullptr;
    if (MODE == 4) pout16 = blockIdx.z ? vt : (u16*)outp;

#pragma unroll
    for (int m = 0; m < 4; ++m) {
        int rbase = row0 + wr * 64 + m * 16 + fg * 4;
#pragma unroll
        for (int n = 0; n < 4; ++n) {
            int col = col0 + wc * 64 + n * 16 + fr;
            float bv = (MODE == 4) ? 0.f : bias[col];
            if (MODE == 1 && col >= 1536) {
                int cc = col - 1536, hh = cc >> 6, dk = cc & 63;
                int s_a = rbase >> 1;
                float v0 = acc[m][n][0] + bv, v1 = acc[m][n][1] + bv;
                float v2 = acc[m][n][2] + bv, v3 = acc[m][n][3] + bv;
                unsigned lo = (unsigned)f2bf(v0) | ((unsigned)f2bf(v2) << 16);
                unsigned hi = (unsigned)f2bf(v1) | ((unsigned)f2bf(v3) << 16);
                *(unsigned*)&vt[((size_t)hh * 64 + dk) * 2048 + s_a] = lo;
                *(unsigned*)&vt[((size_t)(N_HEADS + hh) * 64 + dk) * 2048 + s_a] = hi;
            } else {
#pragma unroll
                for (int r = 0; r < 4; ++r) {
                    int row = rbase + r;
                    float v = acc[m][n][r] + bv;
                    if (MODE == 3) {
                        // fast ELU: expm1(v) = exp2(v*log2e) - 1
                        v = v > 0.f ? v : (fast_exp2(v * 1.44269504f) - 1.f);
                        ((u16*)outp)[(size_t)row * Ncols + col] = f2bf(v);
                    } else if (MODE == 4) {
                        pout16[(size_t)row * 768 + col] = f2bf(v);
                    } else {  // MODE 1, q/k
                        if (col < 768) v *= SLOG2E;   // fold softmax scale+log2e into Q
                        ((u16*)outp)[(size_t)row * QKV_N + col] = f2bf(v);
                    }
                }
            }
        }
    }
}

// ---------------------------------------------------------------------------
// out = res + bf(p0) + bf(p1) + bias   (res may alias out)
// ---------------------------------------------------------------------------
__global__ __launch_bounds__(256) void reduce_add(
    const u16* __restrict__ p0, const u16* __restrict__ p1,
    const float* __restrict__ bias, const float* __restrict__ res,
    float* __restrict__ out)
{
    int i = blockIdx.x * 256 + threadIdx.x;
    int col4 = i % (D_MODEL / 4);
    u64 a = ((const u64*)p0)[i];
    u64 c = ((const u64*)p1)[i];
    float4 o = ((const float4*)res)[i];
    float4 bb = ((const float4*)bias)[col4];
    o.x += bf2f((u16)a)         + bf2f((u16)c)         + bb.x;
    o.y += bf2f((u16)(a >> 16)) + bf2f((u16)(c >> 16)) + bb.y;
    o.z += bf2f((u16)(a >> 32)) + bf2f((u16)(c >> 32)) + bb.z;
    o.w += bf2f((u16)(a >> 48)) + bf2f((u16)(c >> 48)) + bb.w;
    ((float4*)out)[i] = o;
}

// ---------------------------------------------------------------------------
// Flash attention, bf16 MFMA, split-S=2 over blockIdx.z. Partials go into
// DEAD ws regions only (no ws growth): split0 O -> unused V-column slice of
// qkv (ld 2304); split1 O -> z region (ld 768); (m,l) -> dead wqkvb region.
// Softmax path identical to the proven r6 kernel (in-order exp, defer-max,
// ones-trick l, setprio). NOTE: op0 aliases qkv (disjoint columns) -> no
// __restrict__ on qkv/op0.
// ---------------------------------------------------------------------------
__global__ __launch_bounds__(256) void attn_mfma(
    const u16* qkv, const u16* __restrict__ vt,
    u16* op0, u16* __restrict__ op1, float2* __restrict__ mlp)
{
    __shared__ short KsB[2][64 * 64];
    __shared__ short VtB[2][64 * 64];
    __shared__ short PsB[4][16 * 64];

    const int t = threadIdx.x, lane = t & 63, w = t >> 6;
    const int fr = lane & 15, fg = lane >> 4;
    const int fg4 = fg * 4;
    const int qb = blockIdx.x, bh = blockIdx.y, zid = blockIdx.z;
    const int b = bh / N_HEADS, h = bh % N_HEADS;

    short8 qf[2];
    {
        int srow = qb * 64 + w * 16 + fr;
        size_t tok = (size_t)srow * B_SZ + b;
#pragma unroll
        for (int s = 0; s < 2; ++s)
            qf[s] = *(const short8*)(qkv + tok * QKV_N + h * 64 + s * 32 + fg * 8);
    }

    const short8 ones8 = { (short)0x3F80, (short)0x3F80, (short)0x3F80, (short)0x3F80,
                           (short)0x3F80, (short)0x3F80, (short)0x3F80, (short)0x3F80 };

    float m2 = -1e30f;
    f32x4 l_acc = {};
    f32x4 O[4] = {};

    int o0 = w * 1024 + lane * 16;
    int r0 = o0 >> 7,          sl0 = (o0 >> 4) & 7;
    int r1 = (o0 + 4096) >> 7, sl1 = ((o0 + 4096) >> 4) & 7;
    int ss0 = sl0 ^ (r0 & 7), ss1 = sl1 ^ (r1 & 7);
    const u16* kbase = qkv + 768 + h * 64;
    const u16* vtb = vt + (size_t)bh * 64 * S_LEN;
    const int od0 = w * 1024, od1 = w * 1024 + 4096;
    char* Pw = (char*)PsB[w];

    auto stageKV = [&](int c, int kb) {
        gload16(kbase + ((size_t)(kb * 64 + r0) * B_SZ + b) * QKV_N + ss0 * 8, (char*)KsB[c] + od0);
        gload16(kbase + ((size_t)(kb * 64 + r1) * B_SZ + b) * QKV_N + ss1 * 8, (char*)KsB[c] + od1);
        gload16(vtb + (size_t)r0 * S_LEN + kb * 64 + ss0 * 8, (char*)VtB[c] + od0);
        gload16(vtb + (size_t)r1 * S_LEN + kb * 64 + ss1 * 8, (char*)VtB[c] + od1);
    };

    const int kb0 = zid * NTILE;
    stageKV(0, kb0);

    for (int it = 0; it < NTILE; ++it) {
        __syncthreads();
        if (it + 1 < NTILE) stageKV((it + 1) & 1, kb0 + it + 1);
        const char* Ks  = (const char*)KsB[it & 1];
        const char* Vts = (const char*)VtB[it & 1];

        // S'[key][q] = K . Q'^T  (already log2-scaled)
        f32x4 sacc[4] = {};
        __builtin_amdgcn_s_setprio(1);
#pragma unroll
        for (int f = 0; f < 4; ++f) {
            int r = f * 16 + fr;
#pragma unroll
            for (int s = 0; s < 2; ++s) {
                int slot = (s * 4 + fg) ^ (r & 7);
                short8 kf = *(const short8*)(Ks + r * 128 + slot * 16);
                sacc[f] = __builtin_amdgcn_mfma_f32_16x16x32_bf16(kf, qf[s], sacc[f], 0, 0, 0);
            }
        }
        __builtin_amdgcn_s_setprio(0);

        float p[16];
        float mx = -1e30f;
#pragma unroll
        for (int f = 0; f < 4; ++f)
#pragma unroll
            for (int r = 0; r < 4; ++r) {
                float vv = sacc[f][r];
                p[f * 4 + r] = vv;
                mx = fmaxf(mx, vv);
            }
        mx = fmaxf(mx, __shfl_xor(mx, 16));
        mx = fmaxf(mx, __shfl_xor(mx, 32));

        if (!__all(mx - m2 <= 8.f)) {      // defer-max: rescale only on growth
            float mnew = fmaxf(m2, mx);
            float alpha = fast_exp2(m2 - mnew);
            m2 = mnew;
            float a0 = __shfl(alpha, fg4 + 0), a1 = __shfl(alpha, fg4 + 1);
            float a2 = __shfl(alpha, fg4 + 2), a3 = __shfl(alpha, fg4 + 3);
#pragma unroll
            for (int n = 0; n < 4; ++n) {
                O[n][0] *= a0; O[n][1] *= a1; O[n][2] *= a2; O[n][3] *= a3;
            }
            l_acc[0] *= a0; l_acc[1] *= a1; l_acc[2] *= a2; l_acc[3] *= a3;
        }

#pragma unroll
        for (int i = 0; i < 16; ++i)
            p[i] = fast_exp2(p[i] - m2);

        // P -> per-wave swizzled LDS via v_cvt_pk_bf16_f32
#pragma unroll
        for (int f = 0; f < 4; ++f) {
            u32 u0, u1;
            asm("v_cvt_pk_bf16_f32 %0, %1, %2" : "=v"(u0) : "v"(p[4 * f + 0]), "v"(p[4 * f + 1]));
            asm("v_cvt_pk_bf16_f32 %0, %1, %2" : "=v"(u1) : "v"(p[4 * f + 2]), "v"(p[4 * f + 3]));
            int slot = (f * 2 + (fg >> 1)) ^ (fr & 7);
            uint2 uu; uu.x = u0; uu.y = u1;
            *(uint2*)(Pw + fr * 128 + slot * 16 + (fg & 1) * 8) = uu;
        }
        asm volatile("s_waitcnt lgkmcnt(0)" ::: "memory");
        __builtin_amdgcn_sched_barrier(0);

        // O[q][dk] += P[q][key] * V[key][dk];  l_acc += P row-sums (ones trick)
        __builtin_amdgcn_s_setprio(1);
#pragma unroll
        for (int s = 0; s < 2; ++s) {
            int pslot = (s * 4 + fg) ^ (fr & 7);
            short8 pf = *(const short8*)(Pw + fr * 128 + pslot * 16);
            l_acc = __builtin_amdgcn_mfma_f32_16x16x32_bf16(pf, ones8, l_acc, 0, 0, 0);
#pragma unroll
            for (int n = 0; n < 4; ++n) {
                int vrow = n * 16 + fr;
                int vslot = (s * 4 + fg) ^ (vrow & 7);
                short8 vf = *(const short8*)(Vts + vrow * 128 + vslot * 16);
                O[n] = __builtin_amdgcn_mfma_f32_16x16x32_bf16(pf, vf, O[n], 0, 0, 0);
            }
        }
        __builtin_amdgcn_s_setprio(0);
    }

    // partial store: unnormalized O (bf16) + per-row (m, l)
    float mm0 = __shfl(m2, fg4 + 0), mm1 = __shfl(m2, fg4 + 1);
    float mm2 = __shfl(m2, fg4 + 2), mm3 = __shfl(m2, fg4 + 3);
    int srow = qb * 64 + w * 16 + fg4;
    size_t tok0 = (size_t)srow * B_SZ + b;
    u16* op = zid ? op1 : op0;
    const int ld = zid ? 768 : QKV_N;
#pragma unroll
    for (int n = 0; n < 4; ++n) {
        int col = h * 64 + n * 16 + fr;
        op[(tok0 + 0) * ld + col] = f2bf(O[n][0]);
        op[(tok0 + 2) * ld + col] = f2bf(O[n][1]);
        op[(tok0 + 4) * ld + col] = f2bf(O[n][2]);
        op[(tok0 + 6) * ld + col] = f2bf(O[n][3]);
    }
    if (fr == 0) {
        float2* mlz = mlp + (size_t)zid * (N_TOK * N_HEADS);
        mlz[(tok0 + 0) * N_HEADS + h] = make_float2(mm0, l_acc[0]);
        mlz[(tok0 + 2) * N_HEADS + h] = make_float2(mm1, l_acc[1]);
        mlz[(tok0 + 4) * N_HEADS + h] = make_float2(mm2, l_acc[2]);
        mlz[(tok0 + 6) * N_HEADS + h] = make_float2(mm3, l_acc[3]);
    }
}

// ---------------------------------------------------------------------------
// ctx = (a0*O0 + a1*O1) / (a0*l0 + a1*l1),  a_z = 2^(m_z - max(m)).
// op1 aliases ctx (read-before-write per thread) -> no __restrict__ there.
// ---------------------------------------------------------------------------
__global__ __launch_bounds__(256) void combine_attn(
    const u16* __restrict__ op0, const u16* op1,
    const float2* __restrict__ ml, u16* ctx)
{
    int i = blockIdx.x * 256 + threadIdx.x;      // u64 groups, ND/4 total
    int tok = i / 192, c4 = i % 192, h = c4 >> 4;
    float2 q0 = ml[tok * N_HEADS + h];
    float2 q1 = ml[N_TOK * N_HEADS + tok * N_HEADS + h];
    float m = fmaxf(q0.x, q1.x);
    float a0 = fast_exp2(q0.x - m), a1 = fast_exp2(q1.x - m);
    float inv = 1.f / (a0 * q0.y + a1 * q1.y);
    a0 *= inv; a1 *= inv;
    u64 o0 = *(const u64*)(op0 + (size_t)tok * QKV_N + c4 * 4);
    u64 o1 = *(const u64*)(op1 + (size_t)tok * 768 + c4 * 4);
    union { u16 u[4]; u64 ll; } r;
#pragma unroll
    for (int j = 0; j < 4; ++j)
        r.u[j] = f2bf(a0 * bf2f((u16)(o0 >> (16 * j))) +
                      a1 * bf2f((u16)(o1 >> (16 * j))));
    *(u64*)(ctx + (size_t)tok * 768 + c4 * 4) = r.ll;
}

// ---------------------------------------------------------------------------
extern "C" void kernel_launch(void* const* d_in, const int* in_sizes, int n_in,
                              void* d_out, int out_size, void* d_ws, size_t ws_size,
                              hipStream_t stream)
{
    (void)in_sizes; (void)n_in; (void)out_size; (void)ws_size;
    const float* x   = (const float*)d_in[0];
    const float* wq  = (const float*)d_in[1];
    const float* bq  = (const float*)d_in[2];
    const float* wk  = (const float*)d_in[3];
    const float* bk  = (const float*)d_in[4];
    const float* wv  = (const float*)d_in[5];
    const float* bv  = (const float*)d_in[6];
    const float* wo  = (const float*)d_in[7];
    const float* bo  = (const float*)d_in[8];
    const float* g1  = (const float*)d_in[9];
    const float* b1  = (const float*)d_in[10];
    const float* g2  = (const float*)d_in[11];
    const float* b2  = (const float*)d_in[12];
    const float* w1  = (const float*)d_in[13];
    const float* bb1 = (const float*)d_in[14];
    const float* w2  = (const float*)d_in[15];
    const float* bb2 = (const float*)d_in[16];
    float* out = (float*)d_out;

    const size_t ND = (size_t)N_TOK * D_MODEL;
    char* p = (char*)d_ws;
    u16* z    = (u16*)p;                  // z1 / attn-op1 / ctx / z2 ; FFN2 part0
    p += ND * 2;
    u16* qkv  = (u16*)p;                  // qkv (+attn-op0 slice) ; WO partials ; hbuf
    u16* hbuf = (u16*)p;
    p += (size_t)N_TOK * QKV_N * 2;
    u16* vtb  = (u16*)p;
    p += (size_t)B_SZ * N_HEADS * 64 * S_LEN * 2;
    u16* wqkvb = (u16*)p;                 // bf16 weights ; attn ml ; FFN2 part1
    p += (size_t)QKV_N * D_MODEL * 2;
    u16* wob   = (u16*)p; p += (size_t)D_MODEL * D_MODEL * 2;
    u16* w1b   = (u16*)p; p += (size_t)DFF * D_MODEL * 2;
    u16* w2b   = (u16*)p; p += (size_t)D_MODEL * DFF * 2;
    float* biasqkv = (float*)p;

    u16* aop0 = qkv + 1536;     // attn O-partial 0: unused V-cols of qkv (ld 2304)
    u16* aop1 = z;              // attn O-partial 1 (ld 768), becomes ctx
    float2* aml = (float2*)wqkvb;  // attn (m,l) partials (wqkvb dead post-QKV)
    u16* wop0 = qkv;            // WO split-K partials (qkv dead after combine)
    u16* wop1 = qkv + ND;
    u16* fp0  = z;              // FFN2 partials (z, weight regions dead)
    u16* fp1  = wqkvb;

    dim3 blk(256);

    cvt_all<<<6912, blk, 0, stream>>>(wq, wk, wv, wo, w1, w2, wqkvb);
    concat_bias<<<9, blk, 0, stream>>>(bq, bk, bv, biasqkv);

    // z1 = LN(x)
    ln_kernel<<<N_TOK, blk, 0, stream>>>(x, g1, b1, z);
    // qkv = z1 @ Wqkv^T + b  (q scaled, v -> vtb transposed)
    gemm_mfma<1><<<dim3(QKV_N / 128, N_TOK / 128), blk, 0, stream>>>(
        z, wqkvb, biasqkv, qkv, vtb, QKV_N, D_MODEL, D_MODEL, D_MODEL, 0);
    // attention partials (split-S into dead regions), combine -> ctx (= z)
    attn_mfma<<<dim3(S_LEN / 64, B_SZ * N_HEADS, NSPLIT), blk, 0, stream>>>(
        qkv, vtb, aop0, aop1, aml);
    combine_attn<<<(int)(ND / 4 / 256), blk, 0, stream>>>(aop0, aop1, aml, z);
    // WO split-K=2 partials
    gemm_mfma<4><<<dim3(D_MODEL / 128, N_TOK / 128, 2), blk, 0, stream>>>(
        z, wob, nullptr, wop0, wop1, D_MODEL, 384, D_MODEL, D_MODEL, 384);
    // x1 = x + p0 + p1 + bo (fp32 -> out); z2 = LN(x1) (bf16 -> z)
    ln_fuse<<<N_TOK, blk, 0, stream>>>(x, wop0, wop1, bo, g2, b2, out, z);
    // h = ELU(z2 @ w1^T + bb1)  (hbuf overwrites dead WO partials)
    gemm_mfma<3><<<dim3(DFF / 128, N_TOK / 128), blk, 0, stream>>>(
        z, w1b, bb1, hbuf, nullptr, DFF, D_MODEL, D_MODEL, D_MODEL, 0);
    // FFN2 split-K=2 partials
    gemm_mfma<4><<<dim3(D_MODEL / 128, N_TOK / 128, 2), blk, 0, stream>>>(
        hbuf, w2b, nullptr, fp0, fp1, D_MODEL, 1536, DFF, DFF, 1536);
    // out = out(x1) + fp0 + fp1 + bb2
    reduce_add<<<(int)(ND / 4 / 256), blk, 0, stream>>>(fp0, fp1, bb2, out, out);
}